// Round 1
// baseline (2070.449 us; speedup 1.0000x reference)
//
#include <hip/hip_runtime.h>
#include <math.h>

#define NU_    100000
#define NI_    50000
#define NB_    20000
#define DIM    64
#define E_UI_  2000000
#define E_BI_  600000
#define NPROP  (2 * E_UI_)
#define NTOT   (NU_ + NI_)
#define BATCH  4096

// ---------------------------------------------------------------------------
// acc[i] = concat(users_feature, items_feature)[i]
__global__ void init_acc_kernel(const float* __restrict__ uf,
                                const float* __restrict__ itf,
                                float* __restrict__ acc) {
    long long i = (long long)blockIdx.x * blockDim.x + threadIdx.x;
    const long long nu  = (long long)NU_ * DIM;
    const long long tot = (long long)NTOT * DIM;
    if (i < nu)       acc[i] = uf[i];
    else if (i < tot) acc[i] = itf[i - nu];
}

// ---------------------------------------------------------------------------
// Layer-1 SpMM: out[row] += val * feats[col], feats = concat(uf, itf).
// One wave per edge, lane = feature dim.
__global__ void spmm_layer1_kernel(const int*   __restrict__ rows,
                                   const int*   __restrict__ cols,
                                   const float* __restrict__ vals,
                                   const float* __restrict__ uf,
                                   const float* __restrict__ itf,
                                   float* __restrict__ out) {
    long long tid = (long long)blockIdx.x * blockDim.x + threadIdx.x;
    int e    = (int)(tid >> 6);
    int lane = (int)(tid & 63);
    if (e >= NPROP) return;
    int   r = rows[e];          // wave-uniform broadcast load
    int   c = cols[e];
    float v = vals[e];
    float x = (c < NU_) ? uf[(long long)c * DIM + lane]
                        : itf[(long long)(c - NU_) * DIM + lane];
    atomicAdd(&out[(long long)r * DIM + lane], v * x);
}

// ---------------------------------------------------------------------------
// Layer-2 SpMM: accumulate directly into acc (acc += A * f1).
__global__ void spmm_layer2_kernel(const int*   __restrict__ rows,
                                   const int*   __restrict__ cols,
                                   const float* __restrict__ vals,
                                   const float* __restrict__ f1,
                                   float* __restrict__ acc) {
    long long tid = (long long)blockIdx.x * blockDim.x + threadIdx.x;
    int e    = (int)(tid >> 6);
    int lane = (int)(tid & 63);
    if (e >= NPROP) return;
    int   r = rows[e];
    int   c = cols[e];
    float v = vals[e];
    float x = f1[(long long)c * DIM + lane];
    atomicAdd(&acc[(long long)r * DIM + lane], v * x);
}

// ---------------------------------------------------------------------------
// acc += f1
__global__ void acc_add_kernel(float* __restrict__ acc,
                               const float* __restrict__ f1) {
    long long i = (long long)blockIdx.x * blockDim.x + threadIdx.x;
    const long long tot = (long long)NTOT * DIM;
    if (i < tot) acc[i] += f1[i];
}

// ---------------------------------------------------------------------------
// Bundle SpMM: brep[row] += bi_vals[e] * (acc[NU+col] / 3)
__global__ void spmm_bi_kernel(const int*   __restrict__ rows,
                               const int*   __restrict__ cols,
                               const float* __restrict__ vals,
                               const float* __restrict__ acc,
                               float* __restrict__ brep) {
    long long tid = (long long)blockIdx.x * blockDim.x + threadIdx.x;
    int e    = (int)(tid >> 6);
    int lane = (int)(tid & 63);
    if (e >= E_BI_) return;
    int   r = rows[e];
    int   c = cols[e];
    float v = vals[e];
    float x = acc[(long long)(NU_ + c) * DIM + lane] * (1.0f / 3.0f);
    atomicAdd(&brep[(long long)r * DIM + lane], v * x);
}

// ---------------------------------------------------------------------------
// Per-sample BPR loss: one wave per sample.
__global__ void score_kernel(const float* __restrict__ acc,
                             const float* __restrict__ brep,
                             const int*   __restrict__ users,
                             const int*   __restrict__ bundles,
                             float* __restrict__ loss_sum) {
    int tid  = blockIdx.x * blockDim.x + threadIdx.x;
    int b    = tid >> 6;
    int lane = tid & 63;
    if (b >= BATCH) return;
    int u  = users[b];
    int b0 = bundles[2 * b];
    int b1 = bundles[2 * b + 1];
    float du = acc[(long long)u * DIM + lane] * (1.0f / 3.0f);
    float d  = du * (brep[(long long)b0 * DIM + lane] -
                     brep[(long long)b1 * DIM + lane]);
    // wave-64 reduction
    #pragma unroll
    for (int off = 32; off > 0; off >>= 1)
        d += __shfl_down(d, off, 64);
    if (lane == 0) {
        float x = d;                                   // pos - neg
        float l = fmaxf(-x, 0.0f) + log1pf(expf(-fabsf(x)));  // -log_sigmoid(x)
        atomicAdd(loss_sum, l);
    }
}

// ---------------------------------------------------------------------------
__global__ void finalize_kernel(const float* __restrict__ loss_sum,
                                float* __restrict__ out) {
    out[0] = loss_sum[0] * (1.0f / BATCH);
    out[1] = 0.0f;
}

// ---------------------------------------------------------------------------
extern "C" void kernel_launch(void* const* d_in, const int* in_sizes, int n_in,
                              void* d_out, int out_size, void* d_ws, size_t ws_size,
                              hipStream_t stream) {
    const float* uf        = (const float*)d_in[0];   // (NU, D)
    const float* itf       = (const float*)d_in[1];   // (NI, D)
    const float* prop_vals = (const float*)d_in[2];   // (4M,)
    const float* bi_vals   = (const float*)d_in[3];   // (600K,)
    const int*   prop_rows = (const int*)  d_in[4];
    const int*   prop_cols = (const int*)  d_in[5];
    const int*   bi_rows   = (const int*)  d_in[6];
    const int*   bi_cols   = (const int*)  d_in[7];
    const int*   users     = (const int*)  d_in[8];   // (B,1)
    const int*   bundles   = (const int*)  d_in[9];   // (B,2)
    float* out = (float*)d_out;

    // workspace layout (bytes)
    char* ws = (char*)d_ws;
    const size_t ND_BYTES = (size_t)NTOT * DIM * sizeof(float);   // 38.4 MB
    const size_t NB_BYTES = (size_t)NB_  * DIM * sizeof(float);   // 5.12 MB
    float* acc      = (float*)(ws);
    float* f1       = (float*)(ws + ND_BYTES);
    float* brep     = (float*)(ws + 2 * ND_BYTES);
    float* loss_sum = (float*)(ws + 2 * ND_BYTES + NB_BYTES);

    // zero the buffers that are accumulated into (ws is poisoned 0xAA each run)
    hipMemsetAsync(f1,       0, ND_BYTES, stream);
    hipMemsetAsync(brep,     0, NB_BYTES, stream);
    hipMemsetAsync(loss_sum, 0, sizeof(float), stream);

    const int T = 256;
    const long long elemN = (long long)NTOT * DIM;
    dim3 gElem((unsigned)((elemN + T - 1) / T));
    dim3 gProp((unsigned)(((long long)NPROP * 64 + T - 1) / T));
    dim3 gBi  ((unsigned)(((long long)E_BI_ * 64 + T - 1) / T));
    dim3 gScore((unsigned)(((long long)BATCH * 64 + T - 1) / T));

    // acc = feats
    init_acc_kernel<<<gElem, T, 0, stream>>>(uf, itf, acc);
    // f1 = A @ feats
    spmm_layer1_kernel<<<gProp, T, 0, stream>>>(prop_rows, prop_cols, prop_vals,
                                                uf, itf, f1);
    // acc += f1
    acc_add_kernel<<<gElem, T, 0, stream>>>(acc, f1);
    // acc += A @ f1
    spmm_layer2_kernel<<<gProp, T, 0, stream>>>(prop_rows, prop_cols, prop_vals,
                                                f1, acc);
    // brep = B_bi @ (acc_items / 3)
    spmm_bi_kernel<<<gBi, T, 0, stream>>>(bi_rows, bi_cols, bi_vals, acc, brep);
    // per-sample BPR loss -> sum
    score_kernel<<<gScore, T, 0, stream>>>(acc, brep, users, bundles, loss_sum);
    // out = [mean_loss, 0]
    finalize_kernel<<<1, 1, 0, stream>>>(loss_sum, out);
}

// Round 2
// 1476.664 us; speedup vs baseline: 1.4021x; 1.4021x over previous
//
#include <hip/hip_runtime.h>
#include <math.h>

#define NU_    100000
#define NI_    50000
#define NB_    20000
#define DIM    64
#define E_UI_  2000000
#define E_BI_  600000
#define NPROP  (2 * E_UI_)
#define NTOT   (NU_ + NI_)
#define BATCH  4096

// ---------------------------------------------------------------------------
// deg[rows[i]] += 1
__global__ void hist_kernel(const int* __restrict__ rows, int n,
                            int* __restrict__ deg) {
    int i = blockIdx.x * blockDim.x + threadIdx.x;
    if (i < n) atomicAdd(&deg[rows[i]], 1);
}

// ---------------------------------------------------------------------------
// per-256-block sums of deg
__global__ void block_sums_kernel(const int* __restrict__ in, int n,
                                  int* __restrict__ bsums) {
    __shared__ int tmp[256];
    int t = threadIdx.x;
    int i = blockIdx.x * 256 + t;
    tmp[t] = (i < n) ? in[i] : 0;
    __syncthreads();
    for (int o = 128; o > 0; o >>= 1) {
        if (t < o) tmp[t] += tmp[t + o];
        __syncthreads();
    }
    if (t == 0) bsums[blockIdx.x] = tmp[0];
}

// ---------------------------------------------------------------------------
// single-block exclusive scan of bsums (nb <= 1024)
__global__ void scan_bsums_kernel(int* __restrict__ bsums, int nb) {
    __shared__ int tmp[1024];
    int t = threadIdx.x;
    int x = (t < nb) ? bsums[t] : 0;
    tmp[t] = x;
    __syncthreads();
    for (int o = 1; o < 1024; o <<= 1) {
        int y = (t >= o) ? tmp[t - o] : 0;
        __syncthreads();
        tmp[t] += y;
        __syncthreads();
    }
    if (t < nb) bsums[t] = tmp[t] - x;   // exclusive
}

// ---------------------------------------------------------------------------
// off[i] = cursor[i] = bsums_excl[block] + local exclusive scan
__global__ void scan_final_kernel(const int* __restrict__ deg,
                                  const int* __restrict__ bsums, int n,
                                  int* __restrict__ off,
                                  int* __restrict__ cursor) {
    __shared__ int tmp[256];
    int t = threadIdx.x;
    int i = blockIdx.x * 256 + t;
    int x = (i < n) ? deg[i] : 0;
    tmp[t] = x;
    __syncthreads();
    for (int o = 1; o < 256; o <<= 1) {
        int y = (t >= o) ? tmp[t - o] : 0;
        __syncthreads();
        tmp[t] += y;
        __syncthreads();
    }
    if (i < n) {
        int v = bsums[blockIdx.x] + tmp[t] - x;
        off[i] = v;
        cursor[i] = v;
    }
}

// ---------------------------------------------------------------------------
// scatter edge e -> CSR slot; cv = {col, val-bits} packed 8B
__global__ void scatter_kernel(const int* __restrict__ rows,
                               const int* __restrict__ cols,
                               const float* __restrict__ vals, int n,
                               int* __restrict__ cursor,
                               int2* __restrict__ cv) {
    int i = blockIdx.x * blockDim.x + threadIdx.x;
    if (i < n) {
        int pos = atomicAdd(&cursor[rows[i]], 1);
        int2 e;
        e.x = cols[i];
        e.y = __float_as_int(vals[i]);
        cv[pos] = e;
    }
}

// ---------------------------------------------------------------------------
// Layer 1: one wave per row. f1[r] = sum(v * feats[c]); acc[r] = feats[r] + f1[r]
__global__ void layer1_kernel(const int* __restrict__ off,
                              const int* __restrict__ deg,
                              const int2* __restrict__ cv,
                              const float* __restrict__ uf,
                              const float* __restrict__ itf,
                              float* __restrict__ f1,
                              float* __restrict__ acc) {
    int row  = blockIdx.x * (blockDim.x >> 6) + (threadIdx.x >> 6);
    int lane = threadIdx.x & 63;
    if (row >= NTOT) return;
    int s = off[row], d = deg[row];
    float sum = 0.f;
    for (int k = 0; k < d; ++k) {
        int2 e = cv[s + k];                      // wave-uniform 8B load
        float v = __int_as_float(e.y);
        float x = (e.x < NU_) ? uf[(size_t)e.x * DIM + lane]
                              : itf[(size_t)(e.x - NU_) * DIM + lane];
        sum = fmaf(v, x, sum);
    }
    float base = (row < NU_) ? uf[(size_t)row * DIM + lane]
                             : itf[(size_t)(row - NU_) * DIM + lane];
    size_t idx = (size_t)row * DIM + lane;
    f1[idx]  = sum;
    acc[idx] = base + sum;
}

// ---------------------------------------------------------------------------
// Layer 2: acc[r] += sum(v * f1[c]) — wave owns the row, no atomics
__global__ void layer2_kernel(const int* __restrict__ off,
                              const int* __restrict__ deg,
                              const int2* __restrict__ cv,
                              const float* __restrict__ f1,
                              float* __restrict__ acc) {
    int row  = blockIdx.x * (blockDim.x >> 6) + (threadIdx.x >> 6);
    int lane = threadIdx.x & 63;
    if (row >= NTOT) return;
    int s = off[row], d = deg[row];
    float sum = 0.f;
    for (int k = 0; k < d; ++k) {
        int2 e = cv[s + k];
        float v = __int_as_float(e.y);
        sum = fmaf(v, f1[(size_t)e.x * DIM + lane], sum);
    }
    acc[(size_t)row * DIM + lane] += sum;
}

// ---------------------------------------------------------------------------
// Bundle SpMM: brep[r] = (1/3) * sum(v * acc[NU+c])
__global__ void bi_csr_kernel(const int* __restrict__ off,
                              const int* __restrict__ deg,
                              const int2* __restrict__ cv,
                              const float* __restrict__ acc,
                              float* __restrict__ brep) {
    int row  = blockIdx.x * (blockDim.x >> 6) + (threadIdx.x >> 6);
    int lane = threadIdx.x & 63;
    if (row >= NB_) return;
    int s = off[row], d = deg[row];
    float sum = 0.f;
    for (int k = 0; k < d; ++k) {
        int2 e = cv[s + k];
        float v = __int_as_float(e.y);
        sum = fmaf(v, acc[(size_t)(NU_ + e.x) * DIM + lane], sum);
    }
    brep[(size_t)row * DIM + lane] = sum * (1.0f / 3.0f);
}

// ---------------------------------------------------------------------------
// Per-sample BPR loss: one wave per sample.
__global__ void score_kernel(const float* __restrict__ acc,
                             const float* __restrict__ brep,
                             const int*   __restrict__ users,
                             const int*   __restrict__ bundles,
                             float* __restrict__ loss_sum) {
    int tid  = blockIdx.x * blockDim.x + threadIdx.x;
    int b    = tid >> 6;
    int lane = tid & 63;
    if (b >= BATCH) return;
    int u  = users[b];
    int b0 = bundles[2 * b];
    int b1 = bundles[2 * b + 1];
    float du = acc[(size_t)u * DIM + lane] * (1.0f / 3.0f);
    float d  = du * (brep[(size_t)b0 * DIM + lane] -
                     brep[(size_t)b1 * DIM + lane]);
    #pragma unroll
    for (int off = 32; off > 0; off >>= 1)
        d += __shfl_down(d, off, 64);
    if (lane == 0) {
        float x = d;                                          // pos - neg
        float l = fmaxf(-x, 0.0f) + log1pf(expf(-fabsf(x)));  // -log_sigmoid
        atomicAdd(loss_sum, l);
    }
}

// ---------------------------------------------------------------------------
__global__ void finalize_kernel(const float* __restrict__ loss_sum,
                                float* __restrict__ out) {
    out[0] = loss_sum[0] * (1.0f / BATCH);
    out[1] = 0.0f;
}

// ---------------------------------------------------------------------------
extern "C" void kernel_launch(void* const* d_in, const int* in_sizes, int n_in,
                              void* d_out, int out_size, void* d_ws, size_t ws_size,
                              hipStream_t stream) {
    const float* uf        = (const float*)d_in[0];
    const float* itf       = (const float*)d_in[1];
    const float* prop_vals = (const float*)d_in[2];
    const float* bi_vals   = (const float*)d_in[3];
    const int*   prop_rows = (const int*)  d_in[4];
    const int*   prop_cols = (const int*)  d_in[5];
    const int*   bi_rows   = (const int*)  d_in[6];
    const int*   bi_cols   = (const int*)  d_in[7];
    const int*   users     = (const int*)  d_in[8];
    const int*   bundles   = (const int*)  d_in[9];
    float* out = (float*)d_out;

    // ---- workspace layout (all offsets 8B-aligned) ----
    char* ws = (char*)d_ws;
    float* acc   = (float*)(ws + 0);                     // 38.4 MB
    float* f1    = (float*)(ws + 38400000);              // 38.4 MB
    float* brep  = (float*)(ws + 76800000);              // 5.12 MB
    int2*  cvP   = (int2*) (ws + 81920000);              // 32 MB
    int2*  cvB   = (int2*) (ws + 113920000);             // 4.8 MB
    int*   degP  = (int*)  (ws + 118720000);             // 600 KB
    int*   offP  = (int*)  (ws + 119320000);
    int*   curP  = (int*)  (ws + 119920000);
    int*   degB  = (int*)  (ws + 120520000);             // 80 KB
    int*   offB  = (int*)  (ws + 120600000);
    int*   curB  = (int*)  (ws + 120680000);
    int*   bsA   = (int*)  (ws + 120760000);             // 4 KB
    int*   bsB   = (int*)  (ws + 120764096);
    float* loss  = (float*)(ws + 120768192);

    hipMemsetAsync(degP, 0, (size_t)NTOT * 4, stream);
    hipMemsetAsync(degB, 0, (size_t)NB_  * 4, stream);
    hipMemsetAsync(loss, 0, 4, stream);

    const int T = 256;
    const int nbP = (NTOT + 255) / 256;   // 586
    const int nbB = (NB_  + 255) / 256;   // 79

    // ---- build prop CSR ----
    hist_kernel<<<(NPROP + T - 1) / T, T, 0, stream>>>(prop_rows, NPROP, degP);
    block_sums_kernel<<<nbP, 256, 0, stream>>>(degP, NTOT, bsA);
    scan_bsums_kernel<<<1, 1024, 0, stream>>>(bsA, nbP);
    scan_final_kernel<<<nbP, 256, 0, stream>>>(degP, bsA, NTOT, offP, curP);
    scatter_kernel<<<(NPROP + T - 1) / T, T, 0, stream>>>(prop_rows, prop_cols,
                                                          prop_vals, NPROP, curP, cvP);
    // ---- build bi CSR ----
    hist_kernel<<<(E_BI_ + T - 1) / T, T, 0, stream>>>(bi_rows, E_BI_, degB);
    block_sums_kernel<<<nbB, 256, 0, stream>>>(degB, NB_, bsB);
    scan_bsums_kernel<<<1, 1024, 0, stream>>>(bsB, nbB);
    scan_final_kernel<<<nbB, 256, 0, stream>>>(degB, bsB, NB_, offB, curB);
    scatter_kernel<<<(E_BI_ + T - 1) / T, T, 0, stream>>>(bi_rows, bi_cols,
                                                          bi_vals, E_BI_, curB, cvB);

    // ---- propagation (wave per row, 4 rows / 256-thread block) ----
    layer1_kernel<<<(NTOT + 3) / 4, 256, 0, stream>>>(offP, degP, cvP, uf, itf, f1, acc);
    layer2_kernel<<<(NTOT + 3) / 4, 256, 0, stream>>>(offP, degP, cvP, f1, acc);
    bi_csr_kernel<<<(NB_  + 3) / 4, 256, 0, stream>>>(offB, degB, cvB, acc, brep);

    // ---- loss ----
    score_kernel<<<(BATCH * 64 + T - 1) / T, T, 0, stream>>>(acc, brep, users,
                                                             bundles, loss);
    finalize_kernel<<<1, 1, 0, stream>>>(loss, out);
}

// Round 3
// 984.288 us; speedup vs baseline: 2.1035x; 1.5002x over previous
//
#include <hip/hip_runtime.h>
#include <math.h>

#define NU_    100000
#define NI_    50000
#define NB_    20000
#define DIM    64
#define E_UI_  2000000
#define E_BI_  600000
#define NPROP  (2 * E_UI_)
#define NTOT   (NU_ + NI_)
#define BATCH  4096

// ---------------------------------------------------------------------------
// deg[rows[i]] += 1
__global__ void hist_kernel(const int* __restrict__ rows, int n,
                            int* __restrict__ deg) {
    int i = blockIdx.x * blockDim.x + threadIdx.x;
    if (i < n) atomicAdd(&deg[rows[i]], 1);
}

// ---------------------------------------------------------------------------
__global__ void block_sums_kernel(const int* __restrict__ in, int n,
                                  int* __restrict__ bsums) {
    __shared__ int tmp[256];
    int t = threadIdx.x;
    int i = blockIdx.x * 256 + t;
    tmp[t] = (i < n) ? in[i] : 0;
    __syncthreads();
    for (int o = 128; o > 0; o >>= 1) {
        if (t < o) tmp[t] += tmp[t + o];
        __syncthreads();
    }
    if (t == 0) bsums[blockIdx.x] = tmp[0];
}

// ---------------------------------------------------------------------------
__global__ void scan_bsums_kernel(int* __restrict__ bsums, int nb) {
    __shared__ int tmp[1024];
    int t = threadIdx.x;
    int x = (t < nb) ? bsums[t] : 0;
    tmp[t] = x;
    __syncthreads();
    for (int o = 1; o < 1024; o <<= 1) {
        int y = (t >= o) ? tmp[t - o] : 0;
        __syncthreads();
        tmp[t] += y;
        __syncthreads();
    }
    if (t < nb) bsums[t] = tmp[t] - x;   // exclusive
}

// ---------------------------------------------------------------------------
__global__ void scan_final_kernel(const int* __restrict__ deg,
                                  const int* __restrict__ bsums, int n,
                                  int* __restrict__ off,
                                  int* __restrict__ cursor) {
    __shared__ int tmp[256];
    int t = threadIdx.x;
    int i = blockIdx.x * 256 + t;
    int x = (i < n) ? deg[i] : 0;
    tmp[t] = x;
    __syncthreads();
    for (int o = 1; o < 256; o <<= 1) {
        int y = (t >= o) ? tmp[t - o] : 0;
        __syncthreads();
        tmp[t] += y;
        __syncthreads();
    }
    if (i < n) {
        int v = bsums[blockIdx.x] + tmp[t] - x;
        off[i] = v;
        cursor[i] = v;
    }
}

// ---------------------------------------------------------------------------
__global__ void scatter_kernel(const int* __restrict__ rows,
                               const int* __restrict__ cols,
                               const float* __restrict__ vals, int n,
                               int* __restrict__ cursor,
                               int2* __restrict__ cv) {
    int i = blockIdx.x * blockDim.x + threadIdx.x;
    if (i < n) {
        int pos = atomicAdd(&cursor[rows[i]], 1);
        int2 e;
        e.x = cols[i];
        e.y = __float_as_int(vals[i]);
        cv[pos] = e;
    }
}

// ---------------------------------------------------------------------------
// 16 lanes per row, float4 per lane. 4 rows per wave, 16 rows per 256-block.
// Unrolled by 4: up to 16 independent gathers in flight per wave.

__device__ __forceinline__ float4 feat4_cat(const float4* __restrict__ uf4,
                                            const float4* __restrict__ itf4,
                                            int c, int l) {
    const float4* p = (c < NU_) ? (uf4 + (size_t)c * 16)
                                : (itf4 + (size_t)(c - NU_) * 16);
    return p[l];
}

__device__ __forceinline__ void fma4(float4& s, float v, const float4& x) {
    s.x = fmaf(v, x.x, s.x);
    s.y = fmaf(v, x.y, s.y);
    s.z = fmaf(v, x.z, s.z);
    s.w = fmaf(v, x.w, s.w);
}

// Layer 1: f1[r] = sum(v * feats[c]); acc[r] = feats[r] + f1[r]
__global__ void layer1_kernel(const int* __restrict__ off,
                              const int* __restrict__ deg,
                              const int2* __restrict__ cv,
                              const float* __restrict__ uf,
                              const float* __restrict__ itf,
                              float* __restrict__ f1,
                              float* __restrict__ acc) {
    const float4* uf4  = (const float4*)uf;
    const float4* itf4 = (const float4*)itf;
    int wave = blockIdx.x * (blockDim.x >> 6) + (threadIdx.x >> 6);
    int sub  = (threadIdx.x >> 4) & 3;
    int l    = threadIdx.x & 15;
    int row  = wave * 4 + sub;
    if (row >= NTOT) return;
    int s = off[row], d = deg[row];
    float4 sum = make_float4(0.f, 0.f, 0.f, 0.f);
    int k = 0;
    for (; k + 4 <= d; k += 4) {
        int2 e0 = cv[s + k + 0];
        int2 e1 = cv[s + k + 1];
        int2 e2 = cv[s + k + 2];
        int2 e3 = cv[s + k + 3];
        float4 x0 = feat4_cat(uf4, itf4, e0.x, l);
        float4 x1 = feat4_cat(uf4, itf4, e1.x, l);
        float4 x2 = feat4_cat(uf4, itf4, e2.x, l);
        float4 x3 = feat4_cat(uf4, itf4, e3.x, l);
        fma4(sum, __int_as_float(e0.y), x0);
        fma4(sum, __int_as_float(e1.y), x1);
        fma4(sum, __int_as_float(e2.y), x2);
        fma4(sum, __int_as_float(e3.y), x3);
    }
    for (; k < d; ++k) {
        int2 e = cv[s + k];
        float4 x = feat4_cat(uf4, itf4, e.x, l);
        fma4(sum, __int_as_float(e.y), x);
    }
    float4 base = feat4_cat(uf4, itf4, row, l);
    size_t idx = (size_t)row * 16 + l;
    ((float4*)f1)[idx] = sum;
    float4 a;
    a.x = base.x + sum.x; a.y = base.y + sum.y;
    a.z = base.z + sum.z; a.w = base.w + sum.w;
    ((float4*)acc)[idx] = a;
}

// Layer 2: acc[r] += sum(v * f1[c])
__global__ void layer2_kernel(const int* __restrict__ off,
                              const int* __restrict__ deg,
                              const int2* __restrict__ cv,
                              const float* __restrict__ f1,
                              float* __restrict__ acc) {
    const float4* f14 = (const float4*)f1;
    int wave = blockIdx.x * (blockDim.x >> 6) + (threadIdx.x >> 6);
    int sub  = (threadIdx.x >> 4) & 3;
    int l    = threadIdx.x & 15;
    int row  = wave * 4 + sub;
    if (row >= NTOT) return;
    int s = off[row], d = deg[row];
    float4 sum = make_float4(0.f, 0.f, 0.f, 0.f);
    int k = 0;
    for (; k + 4 <= d; k += 4) {
        int2 e0 = cv[s + k + 0];
        int2 e1 = cv[s + k + 1];
        int2 e2 = cv[s + k + 2];
        int2 e3 = cv[s + k + 3];
        float4 x0 = f14[(size_t)e0.x * 16 + l];
        float4 x1 = f14[(size_t)e1.x * 16 + l];
        float4 x2 = f14[(size_t)e2.x * 16 + l];
        float4 x3 = f14[(size_t)e3.x * 16 + l];
        fma4(sum, __int_as_float(e0.y), x0);
        fma4(sum, __int_as_float(e1.y), x1);
        fma4(sum, __int_as_float(e2.y), x2);
        fma4(sum, __int_as_float(e3.y), x3);
    }
    for (; k < d; ++k) {
        int2 e = cv[s + k];
        float4 x = f14[(size_t)e.x * 16 + l];
        fma4(sum, __int_as_float(e.y), x);
    }
    size_t idx = (size_t)row * 16 + l;
    float4 a = ((float4*)acc)[idx];
    a.x += sum.x; a.y += sum.y; a.z += sum.z; a.w += sum.w;
    ((float4*)acc)[idx] = a;
}

// Bundle SpMM: brep[r] = (1/3) * sum(v * acc[NU+c])
__global__ void bi_csr_kernel(const int* __restrict__ off,
                              const int* __restrict__ deg,
                              const int2* __restrict__ cv,
                              const float* __restrict__ acc,
                              float* __restrict__ brep) {
    const float4* acc4 = (const float4*)acc;
    int wave = blockIdx.x * (blockDim.x >> 6) + (threadIdx.x >> 6);
    int sub  = (threadIdx.x >> 4) & 3;
    int l    = threadIdx.x & 15;
    int row  = wave * 4 + sub;
    if (row >= NB_) return;
    int s = off[row], d = deg[row];
    float4 sum = make_float4(0.f, 0.f, 0.f, 0.f);
    int k = 0;
    for (; k + 4 <= d; k += 4) {
        int2 e0 = cv[s + k + 0];
        int2 e1 = cv[s + k + 1];
        int2 e2 = cv[s + k + 2];
        int2 e3 = cv[s + k + 3];
        float4 x0 = acc4[(size_t)(NU_ + e0.x) * 16 + l];
        float4 x1 = acc4[(size_t)(NU_ + e1.x) * 16 + l];
        float4 x2 = acc4[(size_t)(NU_ + e2.x) * 16 + l];
        float4 x3 = acc4[(size_t)(NU_ + e3.x) * 16 + l];
        fma4(sum, __int_as_float(e0.y), x0);
        fma4(sum, __int_as_float(e1.y), x1);
        fma4(sum, __int_as_float(e2.y), x2);
        fma4(sum, __int_as_float(e3.y), x3);
    }
    for (; k < d; ++k) {
        int2 e = cv[s + k];
        float4 x = acc4[(size_t)(NU_ + e.x) * 16 + l];
        fma4(sum, __int_as_float(e.y), x);
    }
    const float c3 = 1.0f / 3.0f;
    sum.x *= c3; sum.y *= c3; sum.z *= c3; sum.w *= c3;
    ((float4*)brep)[(size_t)row * 16 + l] = sum;
}

// ---------------------------------------------------------------------------
__global__ void score_kernel(const float* __restrict__ acc,
                             const float* __restrict__ brep,
                             const int*   __restrict__ users,
                             const int*   __restrict__ bundles,
                             float* __restrict__ loss_sum) {
    int tid  = blockIdx.x * blockDim.x + threadIdx.x;
    int b    = tid >> 6;
    int lane = tid & 63;
    if (b >= BATCH) return;
    int u  = users[b];
    int b0 = bundles[2 * b];
    int b1 = bundles[2 * b + 1];
    float du = acc[(size_t)u * DIM + lane] * (1.0f / 3.0f);
    float d  = du * (brep[(size_t)b0 * DIM + lane] -
                     brep[(size_t)b1 * DIM + lane]);
    #pragma unroll
    for (int off = 32; off > 0; off >>= 1)
        d += __shfl_down(d, off, 64);
    if (lane == 0) {
        float x = d;
        float l = fmaxf(-x, 0.0f) + log1pf(expf(-fabsf(x)));
        atomicAdd(loss_sum, l);
    }
}

// ---------------------------------------------------------------------------
__global__ void finalize_kernel(const float* __restrict__ loss_sum,
                                float* __restrict__ out) {
    out[0] = loss_sum[0] * (1.0f / BATCH);
    out[1] = 0.0f;
}

// ---------------------------------------------------------------------------
extern "C" void kernel_launch(void* const* d_in, const int* in_sizes, int n_in,
                              void* d_out, int out_size, void* d_ws, size_t ws_size,
                              hipStream_t stream) {
    const float* uf        = (const float*)d_in[0];
    const float* itf       = (const float*)d_in[1];
    const float* prop_vals = (const float*)d_in[2];
    const float* bi_vals   = (const float*)d_in[3];
    const int*   prop_rows = (const int*)  d_in[4];
    const int*   prop_cols = (const int*)  d_in[5];
    const int*   bi_rows   = (const int*)  d_in[6];
    const int*   bi_cols   = (const int*)  d_in[7];
    const int*   users     = (const int*)  d_in[8];
    const int*   bundles   = (const int*)  d_in[9];
    float* out = (float*)d_out;

    char* ws = (char*)d_ws;
    float* acc   = (float*)(ws + 0);                     // 38.4 MB
    float* f1    = (float*)(ws + 38400000);              // 38.4 MB
    float* brep  = (float*)(ws + 76800000);              // 5.12 MB
    int2*  cvP   = (int2*) (ws + 81920000);              // 32 MB
    int2*  cvB   = (int2*) (ws + 113920000);             // 4.8 MB
    int*   degP  = (int*)  (ws + 118720000);
    int*   offP  = (int*)  (ws + 119320000);
    int*   curP  = (int*)  (ws + 119920000);
    int*   degB  = (int*)  (ws + 120520000);
    int*   offB  = (int*)  (ws + 120600000);
    int*   curB  = (int*)  (ws + 120680000);
    int*   bsA   = (int*)  (ws + 120760000);
    int*   bsB   = (int*)  (ws + 120764096);
    float* loss  = (float*)(ws + 120768192);

    hipMemsetAsync(degP, 0, (size_t)NTOT * 4, stream);
    hipMemsetAsync(degB, 0, (size_t)NB_  * 4, stream);
    hipMemsetAsync(loss, 0, 4, stream);

    const int T = 256;
    const int nbP = (NTOT + 255) / 256;   // 586
    const int nbB = (NB_  + 255) / 256;   // 79

    // ---- build prop CSR ----
    hist_kernel<<<(NPROP + T - 1) / T, T, 0, stream>>>(prop_rows, NPROP, degP);
    block_sums_kernel<<<nbP, 256, 0, stream>>>(degP, NTOT, bsA);
    scan_bsums_kernel<<<1, 1024, 0, stream>>>(bsA, nbP);
    scan_final_kernel<<<nbP, 256, 0, stream>>>(degP, bsA, NTOT, offP, curP);
    scatter_kernel<<<(NPROP + T - 1) / T, T, 0, stream>>>(prop_rows, prop_cols,
                                                          prop_vals, NPROP, curP, cvP);
    // ---- build bi CSR ----
    hist_kernel<<<(E_BI_ + T - 1) / T, T, 0, stream>>>(bi_rows, E_BI_, degB);
    block_sums_kernel<<<nbB, 256, 0, stream>>>(degB, NB_, bsB);
    scan_bsums_kernel<<<1, 1024, 0, stream>>>(bsB, nbB);
    scan_final_kernel<<<nbB, 256, 0, stream>>>(degB, bsB, NB_, offB, curB);
    scatter_kernel<<<(E_BI_ + T - 1) / T, T, 0, stream>>>(bi_rows, bi_cols,
                                                          bi_vals, E_BI_, curB, cvB);

    // ---- propagation: 16 rows per 256-thread block ----
    layer1_kernel<<<(NTOT + 15) / 16, 256, 0, stream>>>(offP, degP, cvP, uf, itf, f1, acc);
    layer2_kernel<<<(NTOT + 15) / 16, 256, 0, stream>>>(offP, degP, cvP, f1, acc);
    bi_csr_kernel<<<(NB_  + 15) / 16, 256, 0, stream>>>(offB, degB, cvB, acc, brep);

    // ---- loss ----
    score_kernel<<<(BATCH * 64 + T - 1) / T, T, 0, stream>>>(acc, brep, users,
                                                             bundles, loss);
    finalize_kernel<<<1, 1, 0, stream>>>(loss, out);
}

// Round 4
// 925.899 us; speedup vs baseline: 2.2362x; 1.0631x over previous
//
#include <hip/hip_runtime.h>
#include <math.h>

#define NU_    100000
#define NI_    50000
#define NB_    20000
#define DIM    64
#define E_UI_  2000000
#define E_BI_  600000
#define NPROP  (2 * E_UI_)
#define NTOT   (NU_ + NI_)
#define BATCH  4096
#define NBIN_P ((NTOT + 255) / 256)   // 586
#define NBIN_B ((NB_  + 255) / 256)   // 79

// ---------------------------------------------------------------------------
// Merged: global degree histogram + per-bin (row>>8) histogram (LDS-aggregated)
template<int NBIN>
__global__ void hist_bins_kernel(const int* __restrict__ rows, int n,
                                 int* __restrict__ deg,
                                 int* __restrict__ bcnt) {
    __shared__ int lcnt[NBIN];
    for (int i = threadIdx.x; i < NBIN; i += blockDim.x) lcnt[i] = 0;
    __syncthreads();
    int stride = gridDim.x * blockDim.x;
    for (int i = blockIdx.x * blockDim.x + threadIdx.x; i < n; i += stride) {
        int r = rows[i];
        atomicAdd(&deg[r], 1);
        atomicAdd(&lcnt[r >> 8], 1);
    }
    __syncthreads();
    for (int i = threadIdx.x; i < NBIN; i += blockDim.x)
        if (lcnt[i] > 0) atomicAdd(&bcnt[i], lcnt[i]);
}

// ---------------------------------------------------------------------------
// Single-block exclusive scan of bcnt -> binoff, and init gcur = binoff
template<int NBIN>
__global__ void scan_bins_kernel(const int* __restrict__ bcnt,
                                 int* __restrict__ binoff,
                                 int* __restrict__ gcur) {
    __shared__ int tmp[1024];
    int t = threadIdx.x;
    int x = (t < NBIN) ? bcnt[t] : 0;
    tmp[t] = x;
    __syncthreads();
    for (int o = 1; o < 1024; o <<= 1) {
        int y = (t >= o) ? tmp[t - o] : 0;
        __syncthreads();
        tmp[t] += y;
        __syncthreads();
    }
    if (t < NBIN) {
        int v = tmp[t] - x;   // exclusive
        binoff[t] = v;
        gcur[t]   = v;
    }
}

// ---------------------------------------------------------------------------
__global__ void block_sums_kernel(const int* __restrict__ in, int n,
                                  int* __restrict__ bsums) {
    __shared__ int tmp[256];
    int t = threadIdx.x;
    int i = blockIdx.x * 256 + t;
    tmp[t] = (i < n) ? in[i] : 0;
    __syncthreads();
    for (int o = 128; o > 0; o >>= 1) {
        if (t < o) tmp[t] += tmp[t + o];
        __syncthreads();
    }
    if (t == 0) bsums[blockIdx.x] = tmp[0];
}

// ---------------------------------------------------------------------------
__global__ void scan_bsums_kernel(int* __restrict__ bsums, int nb) {
    __shared__ int tmp[1024];
    int t = threadIdx.x;
    int x = (t < nb) ? bsums[t] : 0;
    tmp[t] = x;
    __syncthreads();
    for (int o = 1; o < 1024; o <<= 1) {
        int y = (t >= o) ? tmp[t - o] : 0;
        __syncthreads();
        tmp[t] += y;
        __syncthreads();
    }
    if (t < nb) bsums[t] = tmp[t] - x;   // exclusive
}

// ---------------------------------------------------------------------------
// off[i] = row CSR offset; optionally invs[i] = 1/(sqrt(deg)+1e-8)
__global__ void scan_final_kernel(const int* __restrict__ deg,
                                  const int* __restrict__ bsums, int n,
                                  int* __restrict__ off,
                                  float* __restrict__ invs) {
    __shared__ int tmp[256];
    int t = threadIdx.x;
    int i = blockIdx.x * 256 + t;
    int x = (i < n) ? deg[i] : 0;
    tmp[t] = x;
    __syncthreads();
    for (int o = 1; o < 256; o <<= 1) {
        int y = (t >= o) ? tmp[t - o] : 0;
        __syncthreads();
        tmp[t] += y;
        __syncthreads();
    }
    if (i < n) {
        off[i] = bsums[blockIdx.x] + tmp[t] - x;
        if (invs) invs[i] = 1.0f / (sqrtf((float)x) + 1e-8f);
    }
}

// ---------------------------------------------------------------------------
// Pass 1: LDS-staged multisplit into NBIN bins by row>>8.
// payload = ((row & 255) << 24) | col    (col < 2^24)
template<int NBIN>
__global__ void multisplit_kernel(const int* __restrict__ rows,
                                  const int* __restrict__ cols,
                                  int n,
                                  int* __restrict__ gcur,
                                  unsigned int* __restrict__ binned) {
    constexpr int BUF = 16;
    __shared__ int cnt[NBIN];
    __shared__ int basep[NBIN];
    __shared__ unsigned int stage[NBIN][BUF];
    for (int i = threadIdx.x; i < NBIN; i += blockDim.x) cnt[i] = 0;
    __syncthreads();
    int stride = gridDim.x * blockDim.x;
    for (int base = blockIdx.x * blockDim.x; base < n; base += stride) {
        int i = base + threadIdx.x;
        int bin = 0, pos = -1;
        unsigned int payload = 0;
        if (i < n) {
            int r = rows[i];
            int c = cols[i];
            bin = r >> 8;
            payload = ((unsigned int)(r & 255) << 24) | (unsigned int)c;
            pos = atomicAdd(&cnt[bin], 1);
            if (pos < BUF) stage[bin][pos] = payload;
        }
        __syncthreads();
        if (pos == BUF) basep[bin] = atomicAdd(&gcur[bin], cnt[bin]);
        __syncthreads();
        if (pos >= BUF) {
            binned[basep[bin] + pos] = payload;
            if (pos == BUF) {                 // unique leader per bin
                int b0 = basep[bin];
                #pragma unroll
                for (int j = 0; j < BUF; ++j) binned[b0 + j] = stage[bin][j];
                cnt[bin] = 0;
            }
        }
        __syncthreads();   // resets visible before next iteration's adds
    }
    // drain residual staged entries
    for (int b = threadIdx.x; b < NBIN; b += blockDim.x) {
        int c = cnt[b];
        if (c > 0) {
            int b0 = atomicAdd(&gcur[b], c);
            for (int j = 0; j < c; ++j) binned[b0 + j] = stage[b][j];
        }
    }
}

// ---------------------------------------------------------------------------
// Pass 2: per-bin exact CSR fill. One block per bin; write window ~40 KB.
__global__ void binfill_kernel(const unsigned int* __restrict__ binned,
                               const int* __restrict__ binoff,
                               int n, int nbin, int nrows,
                               const int* __restrict__ off,
                               int* __restrict__ cv) {
    __shared__ int cur[256];
    int b = blockIdx.x;
    int rowbase = b << 8;
    int t = threadIdx.x;
    if (rowbase + t < nrows) cur[t] = off[rowbase + t];
    __syncthreads();
    int s = binoff[b];
    int e = (b + 1 < nbin) ? binoff[b + 1] : n;
    for (int i = s + t; i < e; i += 256) {
        unsigned int p = binned[i];
        int rl = p >> 24;
        int c  = (int)(p & 0xFFFFFFu);
        int slot = atomicAdd(&cur[rl], 1);
        cv[slot] = c;
    }
}

// ---------------------------------------------------------------------------
__device__ __forceinline__ float4 feat4_cat(const float4* __restrict__ uf4,
                                            const float4* __restrict__ itf4,
                                            int c, int l) {
    const float4* p = (c < NU_) ? (uf4 + (size_t)c * 16)
                                : (itf4 + (size_t)(c - NU_) * 16);
    return p[l];
}

__device__ __forceinline__ void fma4(float4& s, float v, const float4& x) {
    s.x = fmaf(v, x.x, s.x);
    s.y = fmaf(v, x.y, s.y);
    s.z = fmaf(v, x.z, s.z);
    s.w = fmaf(v, x.w, s.w);
}

// Layer 1: S = sum(invs[c]*feats[c]); f1 = invs[r]*S;
//          acc[r] = feats[r] + f1;  f1s[r] = invs[r]*f1  (for layer-2 gather)
__global__ void layer1_kernel(const int* __restrict__ off,
                              const int* __restrict__ deg,
                              const int* __restrict__ cv,
                              const float* __restrict__ invs,
                              const float* __restrict__ uf,
                              const float* __restrict__ itf,
                              float* __restrict__ f1s,
                              float* __restrict__ acc) {
    const float4* uf4  = (const float4*)uf;
    const float4* itf4 = (const float4*)itf;
    int wave = blockIdx.x * (blockDim.x >> 6) + (threadIdx.x >> 6);
    int sub  = (threadIdx.x >> 4) & 3;
    int l    = threadIdx.x & 15;
    int row  = wave * 4 + sub;
    if (row >= NTOT) return;
    int s = off[row], d = deg[row];
    float4 sum = make_float4(0.f, 0.f, 0.f, 0.f);
    int k = 0;
    for (; k + 4 <= d; k += 4) {
        int c0 = cv[s + k + 0];
        int c1 = cv[s + k + 1];
        int c2 = cv[s + k + 2];
        int c3 = cv[s + k + 3];
        float w0 = invs[c0], w1 = invs[c1], w2 = invs[c2], w3 = invs[c3];
        float4 x0 = feat4_cat(uf4, itf4, c0, l);
        float4 x1 = feat4_cat(uf4, itf4, c1, l);
        float4 x2 = feat4_cat(uf4, itf4, c2, l);
        float4 x3 = feat4_cat(uf4, itf4, c3, l);
        fma4(sum, w0, x0);
        fma4(sum, w1, x1);
        fma4(sum, w2, x2);
        fma4(sum, w3, x3);
    }
    for (; k < d; ++k) {
        int c = cv[s + k];
        float4 x = feat4_cat(uf4, itf4, c, l);
        fma4(sum, invs[c], x);
    }
    float ivr = invs[row];
    float4 base = feat4_cat(uf4, itf4, row, l);
    size_t idx = (size_t)row * 16 + l;
    float4 f1, a, fs;
    f1.x = ivr * sum.x; f1.y = ivr * sum.y; f1.z = ivr * sum.z; f1.w = ivr * sum.w;
    a.x = base.x + f1.x; a.y = base.y + f1.y; a.z = base.z + f1.z; a.w = base.w + f1.w;
    fs.x = ivr * f1.x; fs.y = ivr * f1.y; fs.z = ivr * f1.z; fs.w = ivr * f1.w;
    ((float4*)acc)[idx] = a;
    ((float4*)f1s)[idx] = fs;
}

// Layer 2: acc[r] += invs[r] * sum(f1s[c])
__global__ void layer2_kernel(const int* __restrict__ off,
                              const int* __restrict__ deg,
                              const int* __restrict__ cv,
                              const float* __restrict__ invs,
                              const float* __restrict__ f1s,
                              float* __restrict__ acc) {
    const float4* fs4 = (const float4*)f1s;
    int wave = blockIdx.x * (blockDim.x >> 6) + (threadIdx.x >> 6);
    int sub  = (threadIdx.x >> 4) & 3;
    int l    = threadIdx.x & 15;
    int row  = wave * 4 + sub;
    if (row >= NTOT) return;
    int s = off[row], d = deg[row];
    float4 sum = make_float4(0.f, 0.f, 0.f, 0.f);
    int k = 0;
    for (; k + 4 <= d; k += 4) {
        int c0 = cv[s + k + 0];
        int c1 = cv[s + k + 1];
        int c2 = cv[s + k + 2];
        int c3 = cv[s + k + 3];
        float4 x0 = fs4[(size_t)c0 * 16 + l];
        float4 x1 = fs4[(size_t)c1 * 16 + l];
        float4 x2 = fs4[(size_t)c2 * 16 + l];
        float4 x3 = fs4[(size_t)c3 * 16 + l];
        sum.x += x0.x + x1.x + x2.x + x3.x;
        sum.y += x0.y + x1.y + x2.y + x3.y;
        sum.z += x0.z + x1.z + x2.z + x3.z;
        sum.w += x0.w + x1.w + x2.w + x3.w;
    }
    for (; k < d; ++k) {
        int c = cv[s + k];
        float4 x = fs4[(size_t)c * 16 + l];
        sum.x += x.x; sum.y += x.y; sum.z += x.z; sum.w += x.w;
    }
    float ivr = invs[row];
    size_t idx = (size_t)row * 16 + l;
    float4 a = ((float4*)acc)[idx];
    a.x = fmaf(ivr, sum.x, a.x);
    a.y = fmaf(ivr, sum.y, a.y);
    a.z = fmaf(ivr, sum.z, a.z);
    a.w = fmaf(ivr, sum.w, a.w);
    ((float4*)acc)[idx] = a;
}

// Bundle SpMM: brep[r] = (1/3) * (1/(degB[r]+1e-8)) * sum(acc[NU+c])
__global__ void bi_csr_kernel(const int* __restrict__ off,
                              const int* __restrict__ deg,
                              const int* __restrict__ cv,
                              const float* __restrict__ acc,
                              float* __restrict__ brep) {
    const float4* acc4 = (const float4*)acc;
    int wave = blockIdx.x * (blockDim.x >> 6) + (threadIdx.x >> 6);
    int sub  = (threadIdx.x >> 4) & 3;
    int l    = threadIdx.x & 15;
    int row  = wave * 4 + sub;
    if (row >= NB_) return;
    int s = off[row], d = deg[row];
    float4 sum = make_float4(0.f, 0.f, 0.f, 0.f);
    int k = 0;
    for (; k + 4 <= d; k += 4) {
        int c0 = cv[s + k + 0];
        int c1 = cv[s + k + 1];
        int c2 = cv[s + k + 2];
        int c3 = cv[s + k + 3];
        float4 x0 = acc4[(size_t)(NU_ + c0) * 16 + l];
        float4 x1 = acc4[(size_t)(NU_ + c1) * 16 + l];
        float4 x2 = acc4[(size_t)(NU_ + c2) * 16 + l];
        float4 x3 = acc4[(size_t)(NU_ + c3) * 16 + l];
        sum.x += x0.x + x1.x + x2.x + x3.x;
        sum.y += x0.y + x1.y + x2.y + x3.y;
        sum.z += x0.z + x1.z + x2.z + x3.z;
        sum.w += x0.w + x1.w + x2.w + x3.w;
    }
    for (; k < d; ++k) {
        int c = cv[s + k];
        float4 x = acc4[(size_t)(NU_ + c) * 16 + l];
        sum.x += x.x; sum.y += x.y; sum.z += x.z; sum.w += x.w;
    }
    float scale = (1.0f / 3.0f) / ((float)d + 1e-8f);
    sum.x *= scale; sum.y *= scale; sum.z *= scale; sum.w *= scale;
    ((float4*)brep)[(size_t)row * 16 + l] = sum;
}

// ---------------------------------------------------------------------------
__global__ void score_kernel(const float* __restrict__ acc,
                             const float* __restrict__ brep,
                             const int*   __restrict__ users,
                             const int*   __restrict__ bundles,
                             float* __restrict__ loss_sum) {
    int tid  = blockIdx.x * blockDim.x + threadIdx.x;
    int b    = tid >> 6;
    int lane = tid & 63;
    if (b >= BATCH) return;
    int u  = users[b];
    int b0 = bundles[2 * b];
    int b1 = bundles[2 * b + 1];
    float du = acc[(size_t)u * DIM + lane] * (1.0f / 3.0f);
    float d  = du * (brep[(size_t)b0 * DIM + lane] -
                     brep[(size_t)b1 * DIM + lane]);
    #pragma unroll
    for (int off = 32; off > 0; off >>= 1)
        d += __shfl_down(d, off, 64);
    if (lane == 0) {
        float x = d;
        float l = fmaxf(-x, 0.0f) + log1pf(expf(-fabsf(x)));
        atomicAdd(loss_sum, l);
    }
}

// ---------------------------------------------------------------------------
__global__ void finalize_kernel(const float* __restrict__ loss_sum,
                                float* __restrict__ out) {
    out[0] = loss_sum[0] * (1.0f / BATCH);
    out[1] = 0.0f;
}

// ---------------------------------------------------------------------------
extern "C" void kernel_launch(void* const* d_in, const int* in_sizes, int n_in,
                              void* d_out, int out_size, void* d_ws, size_t ws_size,
                              hipStream_t stream) {
    const float* uf        = (const float*)d_in[0];
    const float* itf       = (const float*)d_in[1];
    const int*   prop_rows = (const int*)  d_in[4];
    const int*   prop_cols = (const int*)  d_in[5];
    const int*   bi_rows   = (const int*)  d_in[6];
    const int*   bi_cols   = (const int*)  d_in[7];
    const int*   users     = (const int*)  d_in[8];
    const int*   bundles   = (const int*)  d_in[9];
    float* out = (float*)d_out;

    char* ws = (char*)d_ws;
    float*        acc     = (float*)       (ws + 0);           // 38.4 MB
    float*        f1s     = (float*)       (ws + 38400000);    // 38.4 MB
    float*        brep    = (float*)       (ws + 76800000);    // 5.12 MB
    int*          cvP     = (int*)         (ws + 81920000);    // 16 MB
    unsigned int* binnedP = (unsigned int*)(ws + 97920000);    // 16 MB
    int*          cvB     = (int*)         (ws + 113920000);   // 2.4 MB
    unsigned int* binnedB = (unsigned int*)(ws + 116320000);   // 2.4 MB
    int*          degP    = (int*)         (ws + 118720000);
    int*          offP    = (int*)         (ws + 119320000);
    float*        invsP   = (float*)       (ws + 119920000);
    int*          degB    = (int*)         (ws + 120520000);
    int*          offB    = (int*)         (ws + 120600000);
    int*          bcntP   = (int*)         (ws + 120680000);
    int*          binoffP = (int*)         (ws + 120684096);
    int*          gcurP   = (int*)         (ws + 120688192);
    int*          bcntB   = (int*)         (ws + 120692288);
    int*          binoffB = (int*)         (ws + 120696384);
    int*          gcurB   = (int*)         (ws + 120700480);
    int*          bsA     = (int*)         (ws + 120704576);
    int*          bsB     = (int*)         (ws + 120708672);
    float*        loss    = (float*)       (ws + 120712768);

    hipMemsetAsync(degP,  0, (size_t)NTOT * 4, stream);
    hipMemsetAsync(degB,  0, (size_t)NB_  * 4, stream);
    hipMemsetAsync(bcntP, 0, (size_t)NBIN_P * 4, stream);
    hipMemsetAsync(bcntB, 0, (size_t)NBIN_B * 4, stream);
    hipMemsetAsync(loss,  0, 4, stream);

    const int nbP = (NTOT + 255) / 256;   // 586
    const int nbB = (NB_  + 255) / 256;   // 79

    // ---- histograms (deg + bins) ----
    hist_bins_kernel<NBIN_P><<<512, 256, 0, stream>>>(prop_rows, NPROP, degP, bcntP);
    hist_bins_kernel<NBIN_B><<<256, 256, 0, stream>>>(bi_rows, E_BI_, degB, bcntB);

    // ---- bin offsets / cursors ----
    scan_bins_kernel<NBIN_P><<<1, 1024, 0, stream>>>(bcntP, binoffP, gcurP);
    scan_bins_kernel<NBIN_B><<<1, 1024, 0, stream>>>(bcntB, binoffB, gcurB);

    // ---- row offsets (+ invs for prop) ----
    block_sums_kernel<<<nbP, 256, 0, stream>>>(degP, NTOT, bsA);
    scan_bsums_kernel<<<1, 1024, 0, stream>>>(bsA, nbP);
    scan_final_kernel<<<nbP, 256, 0, stream>>>(degP, bsA, NTOT, offP, invsP);
    block_sums_kernel<<<nbB, 256, 0, stream>>>(degB, NB_, bsB);
    scan_bsums_kernel<<<1, 1024, 0, stream>>>(bsB, nbB);
    scan_final_kernel<<<nbB, 256, 0, stream>>>(degB, bsB, NB_, offB, (float*)0);

    // ---- pass 1: staged multisplit ----
    multisplit_kernel<NBIN_P><<<512, 256, 0, stream>>>(prop_rows, prop_cols,
                                                       NPROP, gcurP, binnedP);
    multisplit_kernel<NBIN_B><<<128, 256, 0, stream>>>(bi_rows, bi_cols,
                                                       E_BI_, gcurB, binnedB);

    // ---- pass 2: per-bin CSR fill ----
    binfill_kernel<<<NBIN_P, 256, 0, stream>>>(binnedP, binoffP, NPROP, NBIN_P,
                                               NTOT, offP, cvP);
    binfill_kernel<<<NBIN_B, 256, 0, stream>>>(binnedB, binoffB, E_BI_, NBIN_B,
                                               NB_, offB, cvB);

    // ---- propagation ----
    layer1_kernel<<<(NTOT + 15) / 16, 256, 0, stream>>>(offP, degP, cvP, invsP,
                                                        uf, itf, f1s, acc);
    layer2_kernel<<<(NTOT + 15) / 16, 256, 0, stream>>>(offP, degP, cvP, invsP,
                                                        f1s, acc);
    bi_csr_kernel<<<(NB_ + 15) / 16, 256, 0, stream>>>(offB, degB, cvB, acc, brep);

    // ---- loss ----
    score_kernel<<<BATCH * 64 / 256, 256, 0, stream>>>(acc, brep, users,
                                                       bundles, loss);
    finalize_kernel<<<1, 1, 0, stream>>>(loss, out);
}

// Round 5
// 742.560 us; speedup vs baseline: 2.7883x; 1.2469x over previous
//
#include <hip/hip_runtime.h>
#include <math.h>

#define NU_    100000
#define NI_    50000
#define NB_    20000
#define DIM    64
#define E_UI_  2000000
#define E_BI_  600000
#define NPROP  (2 * E_UI_)
#define NTOT   (NU_ + NI_)
#define BATCH  4096
#define NBIN_P ((NTOT + 255) / 256)   // 586
#define NBIN_B ((NB_  + 255) / 256)   // 79

// ---------------------------------------------------------------------------
// Per-bin (row>>8) histogram only — LDS-aggregated, no global deg atomics.
template<int NBIN>
__global__ void hist_bins_kernel(const int* __restrict__ rows, int n,
                                 int* __restrict__ bcnt) {
    __shared__ int lcnt[NBIN];
    for (int i = threadIdx.x; i < NBIN; i += blockDim.x) lcnt[i] = 0;
    __syncthreads();
    int stride = gridDim.x * blockDim.x;
    for (int i = blockIdx.x * blockDim.x + threadIdx.x; i < n; i += stride)
        atomicAdd(&lcnt[rows[i] >> 8], 1);
    __syncthreads();
    for (int i = threadIdx.x; i < NBIN; i += blockDim.x)
        if (lcnt[i] > 0) atomicAdd(&bcnt[i], lcnt[i]);
}

// ---------------------------------------------------------------------------
// Single-block exclusive scan of bcnt -> binoff, and init gcur = binoff
template<int NBIN>
__global__ void scan_bins_kernel(const int* __restrict__ bcnt,
                                 int* __restrict__ binoff,
                                 int* __restrict__ gcur) {
    __shared__ int tmp[1024];
    int t = threadIdx.x;
    int x = (t < NBIN) ? bcnt[t] : 0;
    tmp[t] = x;
    __syncthreads();
    for (int o = 1; o < 1024; o <<= 1) {
        int y = (t >= o) ? tmp[t - o] : 0;
        __syncthreads();
        tmp[t] += y;
        __syncthreads();
    }
    if (t < NBIN) {
        int v = tmp[t] - x;   // exclusive
        binoff[t] = v;
        gcur[t]   = v;
    }
}

// ---------------------------------------------------------------------------
// Pass 1: LDS-staged multisplit into NBIN bins by row>>8.
// payload = ((row & 255) << 24) | col    (col < 2^24)
template<int NBIN>
__global__ void multisplit_kernel(const int* __restrict__ rows,
                                  const int* __restrict__ cols,
                                  int n,
                                  int* __restrict__ gcur,
                                  unsigned int* __restrict__ binned) {
    constexpr int BUF = 16;
    __shared__ int cnt[NBIN];
    __shared__ int basep[NBIN];
    __shared__ unsigned int stage[NBIN][BUF];
    for (int i = threadIdx.x; i < NBIN; i += blockDim.x) cnt[i] = 0;
    __syncthreads();
    int stride = gridDim.x * blockDim.x;
    for (int base = blockIdx.x * blockDim.x; base < n; base += stride) {
        int i = base + threadIdx.x;
        int bin = 0, pos = -1;
        unsigned int payload = 0;
        if (i < n) {
            int r = rows[i];
            int c = cols[i];
            bin = r >> 8;
            payload = ((unsigned int)(r & 255) << 24) | (unsigned int)c;
            pos = atomicAdd(&cnt[bin], 1);
            if (pos < BUF) stage[bin][pos] = payload;
        }
        __syncthreads();
        if (pos == BUF) basep[bin] = atomicAdd(&gcur[bin], cnt[bin]);
        __syncthreads();
        if (pos >= BUF) {
            binned[basep[bin] + pos] = payload;
            if (pos == BUF) {                 // unique leader per bin
                int b0 = basep[bin];
                #pragma unroll
                for (int j = 0; j < BUF; ++j) binned[b0 + j] = stage[bin][j];
                cnt[bin] = 0;
            }
        }
        __syncthreads();   // resets visible before next iteration's adds
    }
    // drain residual staged entries
    for (int b = threadIdx.x; b < NBIN; b += blockDim.x) {
        int c = cnt[b];
        if (c > 0) {
            int b0 = atomicAdd(&gcur[b], c);
            for (int j = 0; j < c; ++j) binned[b0 + j] = stage[b][j];
        }
    }
}

// ---------------------------------------------------------------------------
// Fused per-bin CSR build: LDS degree count -> LDS scan -> off/deg/invs write
// -> cv fill. One block per bin; all scatter stays in the bin's L2 window.
__global__ void bin_csr_kernel(const unsigned int* __restrict__ binned,
                               const int* __restrict__ binoff,
                               int n, int nbin, int nrows,
                               int* __restrict__ off,
                               int* __restrict__ deg,
                               float* __restrict__ invs,
                               int* __restrict__ cv) {
    __shared__ int cnt[256];
    __shared__ int cur[256];
    __shared__ int scanbuf[256];
    int b = blockIdx.x;
    int t = threadIdx.x;
    int rowbase = b << 8;
    cnt[t] = 0;
    __syncthreads();
    int s = binoff[b];
    int e = (b + 1 < nbin) ? binoff[b + 1] : n;
    for (int i = s + t; i < e; i += 256)
        atomicAdd(&cnt[binned[i] >> 24], 1);
    __syncthreads();
    int x = cnt[t];
    scanbuf[t] = x;
    __syncthreads();
    for (int o = 1; o < 256; o <<= 1) {
        int y = (t >= o) ? scanbuf[t - o] : 0;
        __syncthreads();
        scanbuf[t] += y;
        __syncthreads();
    }
    int base = s + scanbuf[t] - x;   // global CSR offset for row rowbase+t
    cur[t] = base;
    if (rowbase + t < nrows) {
        off[rowbase + t] = base;
        deg[rowbase + t] = x;
        if (invs) invs[rowbase + t] = 1.0f / (sqrtf((float)x) + 1e-8f);
    }
    __syncthreads();
    for (int i = s + t; i < e; i += 256) {
        unsigned int p = binned[i];
        int slot = atomicAdd(&cur[p >> 24], 1);
        cv[slot] = (int)(p & 0xFFFFFFu);
    }
}

// ---------------------------------------------------------------------------
__device__ __forceinline__ float4 feat4_cat(const float4* __restrict__ uf4,
                                            const float4* __restrict__ itf4,
                                            int c, int l) {
    const float4* p = (c < NU_) ? (uf4 + (size_t)c * 16)
                                : (itf4 + (size_t)(c - NU_) * 16);
    return p[l];
}

__device__ __forceinline__ void fma4(float4& s, float v, const float4& x) {
    s.x = fmaf(v, x.x, s.x);
    s.y = fmaf(v, x.y, s.y);
    s.z = fmaf(v, x.z, s.z);
    s.w = fmaf(v, x.w, s.w);
}

// Layer 1: S = sum(invs[c]*feats[c]); f1 = invs[r]*S;
//          acc[r] = feats[r] + f1;  f1s[r] = invs[r]*f1  (for layer-2 gather)
__global__ void layer1_kernel(const int* __restrict__ off,
                              const int* __restrict__ deg,
                              const int* __restrict__ cv,
                              const float* __restrict__ invs,
                              const float* __restrict__ uf,
                              const float* __restrict__ itf,
                              float* __restrict__ f1s,
                              float* __restrict__ acc) {
    const float4* uf4  = (const float4*)uf;
    const float4* itf4 = (const float4*)itf;
    int wave = blockIdx.x * (blockDim.x >> 6) + (threadIdx.x >> 6);
    int sub  = (threadIdx.x >> 4) & 3;
    int l    = threadIdx.x & 15;
    int row  = wave * 4 + sub;
    if (row >= NTOT) return;
    int s = off[row], d = deg[row];
    float4 sum = make_float4(0.f, 0.f, 0.f, 0.f);
    int k = 0;
    for (; k + 4 <= d; k += 4) {
        int c0 = cv[s + k + 0];
        int c1 = cv[s + k + 1];
        int c2 = cv[s + k + 2];
        int c3 = cv[s + k + 3];
        float w0 = invs[c0], w1 = invs[c1], w2 = invs[c2], w3 = invs[c3];
        float4 x0 = feat4_cat(uf4, itf4, c0, l);
        float4 x1 = feat4_cat(uf4, itf4, c1, l);
        float4 x2 = feat4_cat(uf4, itf4, c2, l);
        float4 x3 = feat4_cat(uf4, itf4, c3, l);
        fma4(sum, w0, x0);
        fma4(sum, w1, x1);
        fma4(sum, w2, x2);
        fma4(sum, w3, x3);
    }
    for (; k < d; ++k) {
        int c = cv[s + k];
        float4 x = feat4_cat(uf4, itf4, c, l);
        fma4(sum, invs[c], x);
    }
    float ivr = invs[row];
    float4 base = feat4_cat(uf4, itf4, row, l);
    size_t idx = (size_t)row * 16 + l;
    float4 f1, a, fs;
    f1.x = ivr * sum.x; f1.y = ivr * sum.y; f1.z = ivr * sum.z; f1.w = ivr * sum.w;
    a.x = base.x + f1.x; a.y = base.y + f1.y; a.z = base.z + f1.z; a.w = base.w + f1.w;
    fs.x = ivr * f1.x; fs.y = ivr * f1.y; fs.z = ivr * f1.z; fs.w = ivr * f1.w;
    ((float4*)acc)[idx] = a;
    ((float4*)f1s)[idx] = fs;
}

// Layer 2: acc[r] += invs[r] * sum(f1s[c])
__global__ void layer2_kernel(const int* __restrict__ off,
                              const int* __restrict__ deg,
                              const int* __restrict__ cv,
                              const float* __restrict__ invs,
                              const float* __restrict__ f1s,
                              float* __restrict__ acc) {
    const float4* fs4 = (const float4*)f1s;
    int wave = blockIdx.x * (blockDim.x >> 6) + (threadIdx.x >> 6);
    int sub  = (threadIdx.x >> 4) & 3;
    int l    = threadIdx.x & 15;
    int row  = wave * 4 + sub;
    if (row >= NTOT) return;
    int s = off[row], d = deg[row];
    float4 sum = make_float4(0.f, 0.f, 0.f, 0.f);
    int k = 0;
    for (; k + 4 <= d; k += 4) {
        int c0 = cv[s + k + 0];
        int c1 = cv[s + k + 1];
        int c2 = cv[s + k + 2];
        int c3 = cv[s + k + 3];
        float4 x0 = fs4[(size_t)c0 * 16 + l];
        float4 x1 = fs4[(size_t)c1 * 16 + l];
        float4 x2 = fs4[(size_t)c2 * 16 + l];
        float4 x3 = fs4[(size_t)c3 * 16 + l];
        sum.x += x0.x + x1.x + x2.x + x3.x;
        sum.y += x0.y + x1.y + x2.y + x3.y;
        sum.z += x0.z + x1.z + x2.z + x3.z;
        sum.w += x0.w + x1.w + x2.w + x3.w;
    }
    for (; k < d; ++k) {
        int c = cv[s + k];
        float4 x = fs4[(size_t)c * 16 + l];
        sum.x += x.x; sum.y += x.y; sum.z += x.z; sum.w += x.w;
    }
    float ivr = invs[row];
    size_t idx = (size_t)row * 16 + l;
    float4 a = ((float4*)acc)[idx];
    a.x = fmaf(ivr, sum.x, a.x);
    a.y = fmaf(ivr, sum.y, a.y);
    a.z = fmaf(ivr, sum.z, a.z);
    a.w = fmaf(ivr, sum.w, a.w);
    ((float4*)acc)[idx] = a;
}

// Bundle SpMM: brep[r] = (1/3) * (1/(degB[r]+1e-8)) * sum(acc[NU+c])
__global__ void bi_csr_kernel(const int* __restrict__ off,
                              const int* __restrict__ deg,
                              const int* __restrict__ cv,
                              const float* __restrict__ acc,
                              float* __restrict__ brep) {
    const float4* acc4 = (const float4*)acc;
    int wave = blockIdx.x * (blockDim.x >> 6) + (threadIdx.x >> 6);
    int sub  = (threadIdx.x >> 4) & 3;
    int l    = threadIdx.x & 15;
    int row  = wave * 4 + sub;
    if (row >= NB_) return;
    int s = off[row], d = deg[row];
    float4 sum = make_float4(0.f, 0.f, 0.f, 0.f);
    int k = 0;
    for (; k + 4 <= d; k += 4) {
        int c0 = cv[s + k + 0];
        int c1 = cv[s + k + 1];
        int c2 = cv[s + k + 2];
        int c3 = cv[s + k + 3];
        float4 x0 = acc4[(size_t)(NU_ + c0) * 16 + l];
        float4 x1 = acc4[(size_t)(NU_ + c1) * 16 + l];
        float4 x2 = acc4[(size_t)(NU_ + c2) * 16 + l];
        float4 x3 = acc4[(size_t)(NU_ + c3) * 16 + l];
        sum.x += x0.x + x1.x + x2.x + x3.x;
        sum.y += x0.y + x1.y + x2.y + x3.y;
        sum.z += x0.z + x1.z + x2.z + x3.z;
        sum.w += x0.w + x1.w + x2.w + x3.w;
    }
    for (; k < d; ++k) {
        int c = cv[s + k];
        float4 x = acc4[(size_t)(NU_ + c) * 16 + l];
        sum.x += x.x; sum.y += x.y; sum.z += x.z; sum.w += x.w;
    }
    float scale = (1.0f / 3.0f) / ((float)d + 1e-8f);
    sum.x *= scale; sum.y *= scale; sum.z *= scale; sum.w *= scale;
    ((float4*)brep)[(size_t)row * 16 + l] = sum;
}

// ---------------------------------------------------------------------------
__global__ void score_kernel(const float* __restrict__ acc,
                             const float* __restrict__ brep,
                             const int*   __restrict__ users,
                             const int*   __restrict__ bundles,
                             float* __restrict__ loss_sum) {
    int tid  = blockIdx.x * blockDim.x + threadIdx.x;
    int b    = tid >> 6;
    int lane = tid & 63;
    if (b >= BATCH) return;
    int u  = users[b];
    int b0 = bundles[2 * b];
    int b1 = bundles[2 * b + 1];
    float du = acc[(size_t)u * DIM + lane] * (1.0f / 3.0f);
    float d  = du * (brep[(size_t)b0 * DIM + lane] -
                     brep[(size_t)b1 * DIM + lane]);
    #pragma unroll
    for (int off = 32; off > 0; off >>= 1)
        d += __shfl_down(d, off, 64);
    if (lane == 0) {
        float x = d;
        float l = fmaxf(-x, 0.0f) + log1pf(expf(-fabsf(x)));
        atomicAdd(loss_sum, l);
    }
}

// ---------------------------------------------------------------------------
__global__ void finalize_kernel(const float* __restrict__ loss_sum,
                                float* __restrict__ out) {
    out[0] = loss_sum[0] * (1.0f / BATCH);
    out[1] = 0.0f;
}

// ---------------------------------------------------------------------------
extern "C" void kernel_launch(void* const* d_in, const int* in_sizes, int n_in,
                              void* d_out, int out_size, void* d_ws, size_t ws_size,
                              hipStream_t stream) {
    const float* uf        = (const float*)d_in[0];
    const float* itf       = (const float*)d_in[1];
    const int*   prop_rows = (const int*)  d_in[4];
    const int*   prop_cols = (const int*)  d_in[5];
    const int*   bi_rows   = (const int*)  d_in[6];
    const int*   bi_cols   = (const int*)  d_in[7];
    const int*   users     = (const int*)  d_in[8];
    const int*   bundles   = (const int*)  d_in[9];
    float* out = (float*)d_out;

    char* ws = (char*)d_ws;
    float*        acc     = (float*)       (ws + 0);           // 38.4 MB
    float*        f1s     = (float*)       (ws + 38400000);    // 38.4 MB
    float*        brep    = (float*)       (ws + 76800000);    // 5.12 MB
    int*          cvP     = (int*)         (ws + 81920000);    // 16 MB
    unsigned int* binnedP = (unsigned int*)(ws + 97920000);    // 16 MB
    int*          cvB     = (int*)         (ws + 113920000);   // 2.4 MB
    unsigned int* binnedB = (unsigned int*)(ws + 116320000);   // 2.4 MB
    int*          degP    = (int*)         (ws + 118720000);
    int*          offP    = (int*)         (ws + 119320000);
    float*        invsP   = (float*)       (ws + 119920000);
    int*          degB    = (int*)         (ws + 120520000);
    int*          offB    = (int*)         (ws + 120600000);
    int*          bcntP   = (int*)         (ws + 120680000);
    int*          binoffP = (int*)         (ws + 120684096);
    int*          gcurP   = (int*)         (ws + 120688192);
    int*          bcntB   = (int*)         (ws + 120692288);
    int*          binoffB = (int*)         (ws + 120696384);
    int*          gcurB   = (int*)         (ws + 120700480);
    float*        loss    = (float*)       (ws + 120704576);

    hipMemsetAsync(bcntP, 0, (size_t)NBIN_P * 4, stream);
    hipMemsetAsync(bcntB, 0, (size_t)NBIN_B * 4, stream);
    hipMemsetAsync(loss,  0, 4, stream);

    // ---- bin histograms (LDS only, no global deg atomics) ----
    hist_bins_kernel<NBIN_P><<<512, 256, 0, stream>>>(prop_rows, NPROP, bcntP);
    hist_bins_kernel<NBIN_B><<<256, 256, 0, stream>>>(bi_rows, E_BI_, bcntB);

    // ---- bin offsets / cursors ----
    scan_bins_kernel<NBIN_P><<<1, 1024, 0, stream>>>(bcntP, binoffP, gcurP);
    scan_bins_kernel<NBIN_B><<<1, 1024, 0, stream>>>(bcntB, binoffB, gcurB);

    // ---- pass 1: staged multisplit ----
    multisplit_kernel<NBIN_P><<<512, 256, 0, stream>>>(prop_rows, prop_cols,
                                                       NPROP, gcurP, binnedP);
    multisplit_kernel<NBIN_B><<<128, 256, 0, stream>>>(bi_rows, bi_cols,
                                                       E_BI_, gcurB, binnedB);

    // ---- pass 2: fused per-bin CSR (deg + off + invs + cv) ----
    bin_csr_kernel<<<NBIN_P, 256, 0, stream>>>(binnedP, binoffP, NPROP, NBIN_P,
                                               NTOT, offP, degP, invsP, cvP);
    bin_csr_kernel<<<NBIN_B, 256, 0, stream>>>(binnedB, binoffB, E_BI_, NBIN_B,
                                               NB_, offB, degB, (float*)0, cvB);

    // ---- propagation ----
    layer1_kernel<<<(NTOT + 15) / 16, 256, 0, stream>>>(offP, degP, cvP, invsP,
                                                        uf, itf, f1s, acc);
    layer2_kernel<<<(NTOT + 15) / 16, 256, 0, stream>>>(offP, degP, cvP, invsP,
                                                        f1s, acc);
    bi_csr_kernel<<<(NB_ + 15) / 16, 256, 0, stream>>>(offB, degB, cvB, acc, brep);

    // ---- loss ----
    score_kernel<<<BATCH * 64 / 256, 256, 0, stream>>>(acc, brep, users,
                                                       bundles, loss);
    finalize_kernel<<<1, 1, 0, stream>>>(loss, out);
}

// Round 6
// 620.907 us; speedup vs baseline: 3.3346x; 1.1959x over previous
//
#include <hip/hip_runtime.h>
#include <math.h>

#define NU_    100000
#define NI_    50000
#define NB_    20000
#define DIM    64
#define E_UI_  2000000
#define E_BI_  600000
#define NPROP  (2 * E_UI_)
#define NTOT   (NU_ + NI_)
#define BATCH  4096
#define NBIN_P ((NTOT + 255) / 256)   // 586
#define NBIN_B ((NB_  + 255) / 256)   // 79

// ---------------------------------------------------------------------------
// bf16 helpers
__device__ __forceinline__ float bflo(unsigned int u) {           // low 16 bits
    return __uint_as_float(u << 16);
}
__device__ __forceinline__ float bfhi(unsigned int u) {           // high 16 bits
    return __uint_as_float(u & 0xFFFF0000u);
}
__device__ __forceinline__ unsigned short f2bf(float f) {         // RNE
    unsigned int u = __float_as_uint(f);
    u += 0x7FFFu + ((u >> 16) & 1u);
    return (unsigned short)(u >> 16);
}
__device__ __forceinline__ unsigned int pack2(float a, float b) {
    return (unsigned int)f2bf(a) | ((unsigned int)f2bf(b) << 16);
}

// ---------------------------------------------------------------------------
// Per-bin (row>>8) histogram only — LDS-aggregated, no global deg atomics.
template<int NBIN>
__global__ void hist_bins_kernel(const int* __restrict__ rows, int n,
                                 int* __restrict__ bcnt) {
    __shared__ int lcnt[NBIN];
    for (int i = threadIdx.x; i < NBIN; i += blockDim.x) lcnt[i] = 0;
    __syncthreads();
    int stride = gridDim.x * blockDim.x;
    for (int i = blockIdx.x * blockDim.x + threadIdx.x; i < n; i += stride)
        atomicAdd(&lcnt[rows[i] >> 8], 1);
    __syncthreads();
    for (int i = threadIdx.x; i < NBIN; i += blockDim.x)
        if (lcnt[i] > 0) atomicAdd(&bcnt[i], lcnt[i]);
}

// ---------------------------------------------------------------------------
template<int NBIN>
__global__ void scan_bins_kernel(const int* __restrict__ bcnt,
                                 int* __restrict__ binoff,
                                 int* __restrict__ gcur) {
    __shared__ int tmp[1024];
    int t = threadIdx.x;
    int x = (t < NBIN) ? bcnt[t] : 0;
    tmp[t] = x;
    __syncthreads();
    for (int o = 1; o < 1024; o <<= 1) {
        int y = (t >= o) ? tmp[t - o] : 0;
        __syncthreads();
        tmp[t] += y;
        __syncthreads();
    }
    if (t < NBIN) {
        int v = tmp[t] - x;   // exclusive
        binoff[t] = v;
        gcur[t]   = v;
    }
}

// ---------------------------------------------------------------------------
// Pass 1: LDS-staged multisplit into NBIN bins by row>>8.
// payload = ((row & 255) << 24) | col    (col < 2^24)
template<int NBIN>
__global__ void multisplit_kernel(const int* __restrict__ rows,
                                  const int* __restrict__ cols,
                                  int n,
                                  int* __restrict__ gcur,
                                  unsigned int* __restrict__ binned) {
    constexpr int BUF = 16;
    __shared__ int cnt[NBIN];
    __shared__ int basep[NBIN];
    __shared__ unsigned int stage[NBIN][BUF];
    for (int i = threadIdx.x; i < NBIN; i += blockDim.x) cnt[i] = 0;
    __syncthreads();
    int stride = gridDim.x * blockDim.x;
    for (int base = blockIdx.x * blockDim.x; base < n; base += stride) {
        int i = base + threadIdx.x;
        int bin = 0, pos = -1;
        unsigned int payload = 0;
        if (i < n) {
            int r = rows[i];
            int c = cols[i];
            bin = r >> 8;
            payload = ((unsigned int)(r & 255) << 24) | (unsigned int)c;
            pos = atomicAdd(&cnt[bin], 1);
            if (pos < BUF) stage[bin][pos] = payload;
        }
        __syncthreads();
        if (pos == BUF) basep[bin] = atomicAdd(&gcur[bin], cnt[bin]);
        __syncthreads();
        if (pos >= BUF) {
            binned[basep[bin] + pos] = payload;
            if (pos == BUF) {                 // unique leader per bin
                int b0 = basep[bin];
                #pragma unroll
                for (int j = 0; j < BUF; ++j) binned[b0 + j] = stage[bin][j];
                cnt[bin] = 0;
            }
        }
        __syncthreads();   // resets visible before next iteration's adds
    }
    for (int b = threadIdx.x; b < NBIN; b += blockDim.x) {
        int c = cnt[b];
        if (c > 0) {
            int b0 = atomicAdd(&gcur[b], c);
            for (int j = 0; j < c; ++j) binned[b0 + j] = stage[b][j];
        }
    }
}

// ---------------------------------------------------------------------------
// Fused per-bin CSR build (unchanged from R5).
__global__ void bin_csr_kernel(const unsigned int* __restrict__ binned,
                               const int* __restrict__ binoff,
                               int n, int nbin, int nrows,
                               int* __restrict__ off,
                               int* __restrict__ deg,
                               float* __restrict__ invs,
                               int* __restrict__ cv) {
    __shared__ int cnt[256];
    __shared__ int cur[256];
    __shared__ int scanbuf[256];
    int b = blockIdx.x;
    int t = threadIdx.x;
    int rowbase = b << 8;
    cnt[t] = 0;
    __syncthreads();
    int s = binoff[b];
    int e = (b + 1 < nbin) ? binoff[b + 1] : n;
    for (int i = s + t; i < e; i += 256)
        atomicAdd(&cnt[binned[i] >> 24], 1);
    __syncthreads();
    int x = cnt[t];
    scanbuf[t] = x;
    __syncthreads();
    for (int o = 1; o < 256; o <<= 1) {
        int y = (t >= o) ? scanbuf[t - o] : 0;
        __syncthreads();
        scanbuf[t] += y;
        __syncthreads();
    }
    int base = s + scanbuf[t] - x;
    cur[t] = base;
    if (rowbase + t < nrows) {
        off[rowbase + t] = base;
        deg[rowbase + t] = x;
        if (invs) invs[rowbase + t] = 1.0f / (sqrtf((float)x) + 1e-8f);
    }
    __syncthreads();
    for (int i = s + t; i < e; i += 256) {
        unsigned int p = binned[i];
        int slot = atomicAdd(&cur[p >> 24], 1);
        cv[slot] = (int)(p & 0xFFFFFFu);
    }
}

// ---------------------------------------------------------------------------
// Cast concat(uf, itf) -> bf16. Thread handles 4 floats -> uint2.
__global__ void cast_feats_kernel(const float4* __restrict__ uf4,
                                  const float4* __restrict__ itf4,
                                  uint2* __restrict__ out) {
    int i = blockIdx.x * blockDim.x + threadIdx.x;
    const int nuq = NU_ * 16;          // uf in float4 units
    const int totq = NTOT * 16;
    if (i >= totq) return;
    float4 v = (i < nuq) ? uf4[i] : itf4[i - nuq];
    uint2 o;
    o.x = pack2(v.x, v.y);
    o.y = pack2(v.z, v.w);
    out[i] = o;
}

// ---------------------------------------------------------------------------
// 8 lanes/row, uint4 = 8 bf16 per lane. 8 rows/wave, 32 rows per 256-block.
__device__ __forceinline__ void fma8(float* s, float v, uint4 x) {
    s[0] = fmaf(v, bflo(x.x), s[0]);
    s[1] = fmaf(v, bfhi(x.x), s[1]);
    s[2] = fmaf(v, bflo(x.y), s[2]);
    s[3] = fmaf(v, bfhi(x.y), s[3]);
    s[4] = fmaf(v, bflo(x.z), s[4]);
    s[5] = fmaf(v, bfhi(x.z), s[5]);
    s[6] = fmaf(v, bflo(x.w), s[6]);
    s[7] = fmaf(v, bfhi(x.w), s[7]);
}
__device__ __forceinline__ uint4 pack8(const float* s) {
    uint4 o;
    o.x = pack2(s[0], s[1]);
    o.y = pack2(s[2], s[3]);
    o.z = pack2(s[4], s[5]);
    o.w = pack2(s[6], s[7]);
    return o;
}

// Layer 1: sum = Σ invs[c]·feats[c]; acc16[r] = feats[r] + invs[r]·sum;
//          f1s16[r] = invs[r]²·sum
__global__ void layer1_kernel(const int* __restrict__ off,
                              const int* __restrict__ deg,
                              const int* __restrict__ cv,
                              const float* __restrict__ invs,
                              const uint4* __restrict__ feats16,
                              uint4* __restrict__ f1s16,
                              uint4* __restrict__ acc16) {
    int wave = blockIdx.x * (blockDim.x >> 6) + (threadIdx.x >> 6);
    int sub  = (threadIdx.x >> 3) & 7;
    int l    = threadIdx.x & 7;
    int row  = wave * 8 + sub;
    if (row >= NTOT) return;
    int s = off[row], d = deg[row];
    float sum[8] = {0.f, 0.f, 0.f, 0.f, 0.f, 0.f, 0.f, 0.f};
    int k = 0;
    for (; k + 4 <= d; k += 4) {
        int c0 = cv[s + k + 0];
        int c1 = cv[s + k + 1];
        int c2 = cv[s + k + 2];
        int c3 = cv[s + k + 3];
        float w0 = invs[c0], w1 = invs[c1], w2 = invs[c2], w3 = invs[c3];
        uint4 x0 = feats16[(size_t)c0 * 8 + l];
        uint4 x1 = feats16[(size_t)c1 * 8 + l];
        uint4 x2 = feats16[(size_t)c2 * 8 + l];
        uint4 x3 = feats16[(size_t)c3 * 8 + l];
        fma8(sum, w0, x0);
        fma8(sum, w1, x1);
        fma8(sum, w2, x2);
        fma8(sum, w3, x3);
    }
    for (; k < d; ++k) {
        int c = cv[s + k];
        uint4 x = feats16[(size_t)c * 8 + l];
        fma8(sum, invs[c], x);
    }
    float ivr = invs[row];
    uint4 bx = feats16[(size_t)row * 8 + l];
    float base[8] = {bflo(bx.x), bfhi(bx.x), bflo(bx.y), bfhi(bx.y),
                     bflo(bx.z), bfhi(bx.z), bflo(bx.w), bfhi(bx.w)};
    float a[8], fs[8];
    float iv2 = ivr * ivr;
    #pragma unroll
    for (int j = 0; j < 8; ++j) {
        a[j]  = fmaf(ivr, sum[j], base[j]);
        fs[j] = iv2 * sum[j];
    }
    size_t idx = (size_t)row * 8 + l;
    acc16[idx] = pack8(a);
    f1s16[idx] = pack8(fs);
}

// Layer 2: acc16[r] += invs[r] * Σ f1s16[c]
__global__ void layer2_kernel(const int* __restrict__ off,
                              const int* __restrict__ deg,
                              const int* __restrict__ cv,
                              const float* __restrict__ invs,
                              const uint4* __restrict__ f1s16,
                              uint4* __restrict__ acc16) {
    int wave = blockIdx.x * (blockDim.x >> 6) + (threadIdx.x >> 6);
    int sub  = (threadIdx.x >> 3) & 7;
    int l    = threadIdx.x & 7;
    int row  = wave * 8 + sub;
    if (row >= NTOT) return;
    int s = off[row], d = deg[row];
    float sum[8] = {0.f, 0.f, 0.f, 0.f, 0.f, 0.f, 0.f, 0.f};
    int k = 0;
    for (; k + 4 <= d; k += 4) {
        int c0 = cv[s + k + 0];
        int c1 = cv[s + k + 1];
        int c2 = cv[s + k + 2];
        int c3 = cv[s + k + 3];
        uint4 x0 = f1s16[(size_t)c0 * 8 + l];
        uint4 x1 = f1s16[(size_t)c1 * 8 + l];
        uint4 x2 = f1s16[(size_t)c2 * 8 + l];
        uint4 x3 = f1s16[(size_t)c3 * 8 + l];
        fma8(sum, 1.f, x0);
        fma8(sum, 1.f, x1);
        fma8(sum, 1.f, x2);
        fma8(sum, 1.f, x3);
    }
    for (; k < d; ++k) {
        int c = cv[s + k];
        uint4 x = f1s16[(size_t)c * 8 + l];
        fma8(sum, 1.f, x);
    }
    float ivr = invs[row];
    size_t idx = (size_t)row * 8 + l;
    uint4 ax = acc16[idx];
    float a[8] = {bflo(ax.x), bfhi(ax.x), bflo(ax.y), bfhi(ax.y),
                  bflo(ax.z), bfhi(ax.z), bflo(ax.w), bfhi(ax.w)};
    #pragma unroll
    for (int j = 0; j < 8; ++j) a[j] = fmaf(ivr, sum[j], a[j]);
    acc16[idx] = pack8(a);
}

// Bundle SpMM: brep[r] = (1/3)/(deg+1e-8) * Σ acc16[NU+c]   (fp32 out)
__global__ void bi_csr_kernel(const int* __restrict__ off,
                              const int* __restrict__ deg,
                              const int* __restrict__ cv,
                              const uint4* __restrict__ acc16,
                              float* __restrict__ brep) {
    int wave = blockIdx.x * (blockDim.x >> 6) + (threadIdx.x >> 6);
    int sub  = (threadIdx.x >> 3) & 7;
    int l    = threadIdx.x & 7;
    int row  = wave * 8 + sub;
    if (row >= NB_) return;
    int s = off[row], d = deg[row];
    float sum[8] = {0.f, 0.f, 0.f, 0.f, 0.f, 0.f, 0.f, 0.f};
    int k = 0;
    for (; k + 4 <= d; k += 4) {
        int c0 = cv[s + k + 0];
        int c1 = cv[s + k + 1];
        int c2 = cv[s + k + 2];
        int c3 = cv[s + k + 3];
        uint4 x0 = acc16[(size_t)(NU_ + c0) * 8 + l];
        uint4 x1 = acc16[(size_t)(NU_ + c1) * 8 + l];
        uint4 x2 = acc16[(size_t)(NU_ + c2) * 8 + l];
        uint4 x3 = acc16[(size_t)(NU_ + c3) * 8 + l];
        fma8(sum, 1.f, x0);
        fma8(sum, 1.f, x1);
        fma8(sum, 1.f, x2);
        fma8(sum, 1.f, x3);
    }
    for (; k < d; ++k) {
        int c = cv[s + k];
        uint4 x = acc16[(size_t)(NU_ + c) * 8 + l];
        fma8(sum, 1.f, x);
    }
    float scale = (1.0f / 3.0f) / ((float)d + 1e-8f);
    float4 o0, o1;
    o0.x = sum[0] * scale; o0.y = sum[1] * scale;
    o0.z = sum[2] * scale; o0.w = sum[3] * scale;
    o1.x = sum[4] * scale; o1.y = sum[5] * scale;
    o1.z = sum[6] * scale; o1.w = sum[7] * scale;
    float4* bp = (float4*)(brep + (size_t)row * DIM + l * 8);
    bp[0] = o0;
    bp[1] = o1;
}

// ---------------------------------------------------------------------------
__global__ void score_kernel(const unsigned short* __restrict__ acc16u,
                             const float* __restrict__ brep,
                             const int*   __restrict__ users,
                             const int*   __restrict__ bundles,
                             float* __restrict__ loss_sum) {
    int tid  = blockIdx.x * blockDim.x + threadIdx.x;
    int b    = tid >> 6;
    int lane = tid & 63;
    if (b >= BATCH) return;
    int u  = users[b];
    int b0 = bundles[2 * b];
    int b1 = bundles[2 * b + 1];
    float du = __uint_as_float((unsigned int)acc16u[(size_t)u * DIM + lane] << 16)
               * (1.0f / 3.0f);
    float d  = du * (brep[(size_t)b0 * DIM + lane] -
                     brep[(size_t)b1 * DIM + lane]);
    #pragma unroll
    for (int off = 32; off > 0; off >>= 1)
        d += __shfl_down(d, off, 64);
    if (lane == 0) {
        float x = d;
        float l = fmaxf(-x, 0.0f) + log1pf(expf(-fabsf(x)));
        atomicAdd(loss_sum, l);
    }
}

// ---------------------------------------------------------------------------
__global__ void finalize_kernel(const float* __restrict__ loss_sum,
                                float* __restrict__ out) {
    out[0] = loss_sum[0] * (1.0f / BATCH);
    out[1] = 0.0f;
}

// ---------------------------------------------------------------------------
extern "C" void kernel_launch(void* const* d_in, const int* in_sizes, int n_in,
                              void* d_out, int out_size, void* d_ws, size_t ws_size,
                              hipStream_t stream) {
    const float* uf        = (const float*)d_in[0];
    const float* itf       = (const float*)d_in[1];
    const int*   prop_rows = (const int*)  d_in[4];
    const int*   prop_cols = (const int*)  d_in[5];
    const int*   bi_rows   = (const int*)  d_in[6];
    const int*   bi_cols   = (const int*)  d_in[7];
    const int*   users     = (const int*)  d_in[8];
    const int*   bundles   = (const int*)  d_in[9];
    float* out = (float*)d_out;

    char* ws = (char*)d_ws;
    uint4*        acc16   = (uint4*)       (ws + 0);           // 19.2 MB
    uint4*        f1s16   = (uint4*)       (ws + 19200000);    // 19.2 MB
    uint4*        feats16 = (uint4*)       (ws + 38400000);    // 19.2 MB
    float*        brep    = (float*)       (ws + 57600000);    // 5.12 MB
    int*          cvP     = (int*)         (ws + 62720000);    // 16 MB
    unsigned int* binnedP = (unsigned int*)(ws + 78720000);    // 16 MB
    int*          cvB     = (int*)         (ws + 94720000);    // 2.4 MB
    unsigned int* binnedB = (unsigned int*)(ws + 97120000);    // 2.4 MB
    int*          degP    = (int*)         (ws + 99520000);
    int*          offP    = (int*)         (ws + 100120000);
    float*        invsP   = (float*)       (ws + 100720000);
    int*          degB    = (int*)         (ws + 101320000);
    int*          offB    = (int*)         (ws + 101400000);
    int*          bcntP   = (int*)         (ws + 101480000);
    int*          binoffP = (int*)         (ws + 101484096);
    int*          gcurP   = (int*)         (ws + 101488192);
    int*          bcntB   = (int*)         (ws + 101492288);
    int*          binoffB = (int*)         (ws + 101496384);
    int*          gcurB   = (int*)         (ws + 101500480);
    float*        loss    = (float*)       (ws + 101504576);

    hipMemsetAsync(bcntP, 0, (size_t)NBIN_P * 4, stream);
    hipMemsetAsync(bcntB, 0, (size_t)NBIN_B * 4, stream);
    hipMemsetAsync(loss,  0, 4, stream);

    // ---- bf16 cast of features ----
    cast_feats_kernel<<<(NTOT * 16 + 255) / 256, 256, 0, stream>>>(
        (const float4*)uf, (const float4*)itf, (uint2*)feats16);

    // ---- bin histograms ----
    hist_bins_kernel<NBIN_P><<<512, 256, 0, stream>>>(prop_rows, NPROP, bcntP);
    hist_bins_kernel<NBIN_B><<<256, 256, 0, stream>>>(bi_rows, E_BI_, bcntB);

    // ---- bin offsets / cursors ----
    scan_bins_kernel<NBIN_P><<<1, 1024, 0, stream>>>(bcntP, binoffP, gcurP);
    scan_bins_kernel<NBIN_B><<<1, 1024, 0, stream>>>(bcntB, binoffB, gcurB);

    // ---- pass 1: staged multisplit ----
    multisplit_kernel<NBIN_P><<<512, 256, 0, stream>>>(prop_rows, prop_cols,
                                                       NPROP, gcurP, binnedP);
    multisplit_kernel<NBIN_B><<<128, 256, 0, stream>>>(bi_rows, bi_cols,
                                                       E_BI_, gcurB, binnedB);

    // ---- pass 2: fused per-bin CSR ----
    bin_csr_kernel<<<NBIN_P, 256, 0, stream>>>(binnedP, binoffP, NPROP, NBIN_P,
                                               NTOT, offP, degP, invsP, cvP);
    bin_csr_kernel<<<NBIN_B, 256, 0, stream>>>(binnedB, binoffB, E_BI_, NBIN_B,
                                               NB_, offB, degB, (float*)0, cvB);

    // ---- propagation: 32 rows per 256-thread block ----
    layer1_kernel<<<(NTOT + 31) / 32, 256, 0, stream>>>(offP, degP, cvP, invsP,
                                                        feats16, f1s16, acc16);
    layer2_kernel<<<(NTOT + 31) / 32, 256, 0, stream>>>(offP, degP, cvP, invsP,
                                                        f1s16, acc16);
    bi_csr_kernel<<<(NB_ + 31) / 32, 256, 0, stream>>>(offB, degB, cvB, acc16, brep);

    // ---- loss ----
    score_kernel<<<BATCH * 64 / 256, 256, 0, stream>>>(
        (const unsigned short*)acc16, brep, users, bundles, loss);
    finalize_kernel<<<1, 1, 0, stream>>>(loss, out);
}

// Round 7
// 556.809 us; speedup vs baseline: 3.7184x; 1.1151x over previous
//
#include <hip/hip_runtime.h>
#include <math.h>

#define NU_    100000
#define NI_    50000
#define NB_    20000
#define DIM    64
#define E_UI_  2000000
#define E_BI_  600000
#define NPROP  (2 * E_UI_)
#define NTOT   (NU_ + NI_)
#define BATCH  4096
#define NBIN_P ((NTOT + 255) / 256)   // 586
#define NBIN_B ((NB_  + 255) / 256)   // 79

// ---------------------------------------------------------------------------
// bf16 helpers
__device__ __forceinline__ float bflo(unsigned int u) {           // low 16 bits
    return __uint_as_float(u << 16);
}
__device__ __forceinline__ float bfhi(unsigned int u) {           // high 16 bits
    return __uint_as_float(u & 0xFFFF0000u);
}
__device__ __forceinline__ unsigned short f2bf(float f) {         // RNE
    unsigned int u = __float_as_uint(f);
    u += 0x7FFFu + ((u >> 16) & 1u);
    return (unsigned short)(u >> 16);
}
__device__ __forceinline__ unsigned int pack2(float a, float b) {
    return (unsigned int)f2bf(a) | ((unsigned int)f2bf(b) << 16);
}

// ---------------------------------------------------------------------------
// Per-bin (row>>8) histogram — LDS-aggregated, unrolled 4/thread.
template<int NBIN>
__global__ void hist_bins_kernel(const int* __restrict__ rows, int n,
                                 int* __restrict__ bcnt) {
    __shared__ int lcnt[NBIN];
    for (int i = threadIdx.x; i < NBIN; i += blockDim.x) lcnt[i] = 0;
    __syncthreads();
    int stride = gridDim.x * blockDim.x * 4;
    for (int base = blockIdx.x * blockDim.x * 4; base < n; base += stride) {
        #pragma unroll
        for (int j = 0; j < 4; ++j) {
            int i = base + j * blockDim.x + threadIdx.x;
            if (i < n) atomicAdd(&lcnt[rows[i] >> 8], 1);
        }
    }
    __syncthreads();
    for (int i = threadIdx.x; i < NBIN; i += blockDim.x)
        if (lcnt[i] > 0) atomicAdd(&bcnt[i], lcnt[i]);
}

// ---------------------------------------------------------------------------
template<int NBIN>
__global__ void scan_bins_kernel(const int* __restrict__ bcnt,
                                 int* __restrict__ binoff,
                                 int* __restrict__ gcur) {
    __shared__ int tmp[1024];
    int t = threadIdx.x;
    int x = (t < NBIN) ? bcnt[t] : 0;
    tmp[t] = x;
    __syncthreads();
    for (int o = 1; o < 1024; o <<= 1) {
        int y = (t >= o) ? tmp[t - o] : 0;
        __syncthreads();
        tmp[t] += y;
        __syncthreads();
    }
    if (t < NBIN) {
        int v = tmp[t] - x;   // exclusive
        binoff[t] = v;
        gcur[t]   = v;
    }
}

// ---------------------------------------------------------------------------
// Pass 1: LDS-staged multisplit into NBIN bins by row>>8, 4 edges/thread per
// barrier cycle. payload = ((row & 255) << 24) | col    (col < 2^24)
template<int NBIN>
__global__ void multisplit_kernel(const int* __restrict__ rows,
                                  const int* __restrict__ cols,
                                  int n,
                                  int* __restrict__ gcur,
                                  unsigned int* __restrict__ binned) {
    constexpr int BUF = 16;
    __shared__ int cnt[NBIN];
    __shared__ int basep[NBIN];
    __shared__ unsigned int stage[NBIN][BUF];
    for (int i = threadIdx.x; i < NBIN; i += blockDim.x) cnt[i] = 0;
    __syncthreads();
    int stride = gridDim.x * blockDim.x * 4;
    for (int base = blockIdx.x * blockDim.x * 4; base < n; base += stride) {
        int bin[4], pos[4];
        unsigned int payload[4];
        #pragma unroll
        for (int j = 0; j < 4; ++j) {
            int i = base + j * blockDim.x + threadIdx.x;   // coalesced per step
            pos[j] = -1;
            if (i < n) {
                int r = rows[i];
                int c = cols[i];
                bin[j] = r >> 8;
                payload[j] = ((unsigned int)(r & 255) << 24) | (unsigned int)c;
                pos[j] = atomicAdd(&cnt[bin[j]], 1);
                if (pos[j] < BUF) stage[bin[j]][pos[j]] = payload[j];
            }
        }
        __syncthreads();
        #pragma unroll
        for (int j = 0; j < 4; ++j)
            if (pos[j] == BUF)                 // unique leader per bin
                basep[bin[j]] = atomicAdd(&gcur[bin[j]], cnt[bin[j]]);
        __syncthreads();
        #pragma unroll
        for (int j = 0; j < 4; ++j) {
            if (pos[j] >= BUF) {
                binned[basep[bin[j]] + pos[j]] = payload[j];
                if (pos[j] == BUF) {
                    int b0 = basep[bin[j]];
                    #pragma unroll
                    for (int q = 0; q < BUF; ++q) binned[b0 + q] = stage[bin[j]][q];
                    cnt[bin[j]] = 0;
                }
            }
        }
        __syncthreads();   // resets visible before next iteration's adds
    }
    // drain residual staged entries
    for (int b = threadIdx.x; b < NBIN; b += blockDim.x) {
        int c = cnt[b];
        if (c > 0) {
            int b0 = atomicAdd(&gcur[b], c);
            for (int j = 0; j < c; ++j) binned[b0 + j] = stage[b][j];
        }
    }
}

// ---------------------------------------------------------------------------
// Fused per-bin CSR build (unchanged).
__global__ void bin_csr_kernel(const unsigned int* __restrict__ binned,
                               const int* __restrict__ binoff,
                               int n, int nbin, int nrows,
                               int* __restrict__ off,
                               int* __restrict__ deg,
                               float* __restrict__ invs,
                               int* __restrict__ cv) {
    __shared__ int cnt[256];
    __shared__ int cur[256];
    __shared__ int scanbuf[256];
    int b = blockIdx.x;
    int t = threadIdx.x;
    int rowbase = b << 8;
    cnt[t] = 0;
    __syncthreads();
    int s = binoff[b];
    int e = (b + 1 < nbin) ? binoff[b + 1] : n;
    for (int i = s + t; i < e; i += 256)
        atomicAdd(&cnt[binned[i] >> 24], 1);
    __syncthreads();
    int x = cnt[t];
    scanbuf[t] = x;
    __syncthreads();
    for (int o = 1; o < 256; o <<= 1) {
        int y = (t >= o) ? scanbuf[t - o] : 0;
        __syncthreads();
        scanbuf[t] += y;
        __syncthreads();
    }
    int base = s + scanbuf[t] - x;
    cur[t] = base;
    if (rowbase + t < nrows) {
        off[rowbase + t] = base;
        deg[rowbase + t] = x;
        if (invs) invs[rowbase + t] = 1.0f / (sqrtf((float)x) + 1e-8f);
    }
    __syncthreads();
    for (int i = s + t; i < e; i += 256) {
        unsigned int p = binned[i];
        int slot = atomicAdd(&cur[p >> 24], 1);
        cv[slot] = (int)(p & 0xFFFFFFu);
    }
}

// ---------------------------------------------------------------------------
// Cast concat(uf, itf) -> bf16. Thread handles 4 floats -> uint2.
__global__ void cast_feats_kernel(const float4* __restrict__ uf4,
                                  const float4* __restrict__ itf4,
                                  uint2* __restrict__ out) {
    int i = blockIdx.x * blockDim.x + threadIdx.x;
    const int nuq = NU_ * 16;          // uf in float4 units
    const int totq = NTOT * 16;
    if (i >= totq) return;
    float4 v = (i < nuq) ? uf4[i] : itf4[i - nuq];
    uint2 o;
    o.x = pack2(v.x, v.y);
    o.y = pack2(v.z, v.w);
    out[i] = o;
}

// ---------------------------------------------------------------------------
// 8 lanes/row, uint4 = 8 bf16 per lane. 8 rows/wave, 32 rows per 256-block.
__device__ __forceinline__ void fma8(float* s, float v, uint4 x) {
    s[0] = fmaf(v, bflo(x.x), s[0]);
    s[1] = fmaf(v, bfhi(x.x), s[1]);
    s[2] = fmaf(v, bflo(x.y), s[2]);
    s[3] = fmaf(v, bfhi(x.y), s[3]);
    s[4] = fmaf(v, bflo(x.z), s[4]);
    s[5] = fmaf(v, bfhi(x.z), s[5]);
    s[6] = fmaf(v, bflo(x.w), s[6]);
    s[7] = fmaf(v, bfhi(x.w), s[7]);
}
__device__ __forceinline__ uint4 pack8(const float* s) {
    uint4 o;
    o.x = pack2(s[0], s[1]);
    o.y = pack2(s[2], s[3]);
    o.z = pack2(s[4], s[5]);
    o.w = pack2(s[6], s[7]);
    return o;
}

// Layer 1: sum = Σ invs[c]·feats[c]; acc16[r] = feats[r] + invs[r]·sum;
//          f1s16[r] = invs[r]²·sum
__global__ void layer1_kernel(const int* __restrict__ off,
                              const int* __restrict__ deg,
                              const int* __restrict__ cv,
                              const float* __restrict__ invs,
                              const uint4* __restrict__ feats16,
                              uint4* __restrict__ f1s16,
                              uint4* __restrict__ acc16) {
    int wave = blockIdx.x * (blockDim.x >> 6) + (threadIdx.x >> 6);
    int sub  = (threadIdx.x >> 3) & 7;
    int l    = threadIdx.x & 7;
    int row  = wave * 8 + sub;
    if (row >= NTOT) return;
    int s = off[row], d = deg[row];
    float sum[8] = {0.f, 0.f, 0.f, 0.f, 0.f, 0.f, 0.f, 0.f};
    int k = 0;
    for (; k + 4 <= d; k += 4) {
        int c0 = cv[s + k + 0];
        int c1 = cv[s + k + 1];
        int c2 = cv[s + k + 2];
        int c3 = cv[s + k + 3];
        float w0 = invs[c0], w1 = invs[c1], w2 = invs[c2], w3 = invs[c3];
        uint4 x0 = feats16[(size_t)c0 * 8 + l];
        uint4 x1 = feats16[(size_t)c1 * 8 + l];
        uint4 x2 = feats16[(size_t)c2 * 8 + l];
        uint4 x3 = feats16[(size_t)c3 * 8 + l];
        fma8(sum, w0, x0);
        fma8(sum, w1, x1);
        fma8(sum, w2, x2);
        fma8(sum, w3, x3);
    }
    for (; k < d; ++k) {
        int c = cv[s + k];
        uint4 x = feats16[(size_t)c * 8 + l];
        fma8(sum, invs[c], x);
    }
    float ivr = invs[row];
    uint4 bx = feats16[(size_t)row * 8 + l];
    float base[8] = {bflo(bx.x), bfhi(bx.x), bflo(bx.y), bfhi(bx.y),
                     bflo(bx.z), bfhi(bx.z), bflo(bx.w), bfhi(bx.w)};
    float a[8], fs[8];
    float iv2 = ivr * ivr;
    #pragma unroll
    for (int j = 0; j < 8; ++j) {
        a[j]  = fmaf(ivr, sum[j], base[j]);
        fs[j] = iv2 * sum[j];
    }
    size_t idx = (size_t)row * 8 + l;
    acc16[idx] = pack8(a);
    f1s16[idx] = pack8(fs);
}

// Layer 2: acc16[r] += invs[r] * Σ f1s16[c]
__global__ void layer2_kernel(const int* __restrict__ off,
                              const int* __restrict__ deg,
                              const int* __restrict__ cv,
                              const float* __restrict__ invs,
                              const uint4* __restrict__ f1s16,
                              uint4* __restrict__ acc16) {
    int wave = blockIdx.x * (blockDim.x >> 6) + (threadIdx.x >> 6);
    int sub  = (threadIdx.x >> 3) & 7;
    int l    = threadIdx.x & 7;
    int row  = wave * 8 + sub;
    if (row >= NTOT) return;
    int s = off[row], d = deg[row];
    float sum[8] = {0.f, 0.f, 0.f, 0.f, 0.f, 0.f, 0.f, 0.f};
    int k = 0;
    for (; k + 4 <= d; k += 4) {
        int c0 = cv[s + k + 0];
        int c1 = cv[s + k + 1];
        int c2 = cv[s + k + 2];
        int c3 = cv[s + k + 3];
        uint4 x0 = f1s16[(size_t)c0 * 8 + l];
        uint4 x1 = f1s16[(size_t)c1 * 8 + l];
        uint4 x2 = f1s16[(size_t)c2 * 8 + l];
        uint4 x3 = f1s16[(size_t)c3 * 8 + l];
        fma8(sum, 1.f, x0);
        fma8(sum, 1.f, x1);
        fma8(sum, 1.f, x2);
        fma8(sum, 1.f, x3);
    }
    for (; k < d; ++k) {
        int c = cv[s + k];
        uint4 x = f1s16[(size_t)c * 8 + l];
        fma8(sum, 1.f, x);
    }
    float ivr = invs[row];
    size_t idx = (size_t)row * 8 + l;
    uint4 ax = acc16[idx];
    float a[8] = {bflo(ax.x), bfhi(ax.x), bflo(ax.y), bfhi(ax.y),
                  bflo(ax.z), bfhi(ax.z), bflo(ax.w), bfhi(ax.w)};
    #pragma unroll
    for (int j = 0; j < 8; ++j) a[j] = fmaf(ivr, sum[j], a[j]);
    acc16[idx] = pack8(a);
}

// Bundle SpMM: brep[r] = (1/3)/(deg+1e-8) * Σ acc16[NU+c]   (fp32 out)
__global__ void bi_csr_kernel(const int* __restrict__ off,
                              const int* __restrict__ deg,
                              const int* __restrict__ cv,
                              const uint4* __restrict__ acc16,
                              float* __restrict__ brep) {
    int wave = blockIdx.x * (blockDim.x >> 6) + (threadIdx.x >> 6);
    int sub  = (threadIdx.x >> 3) & 7;
    int l    = threadIdx.x & 7;
    int row  = wave * 8 + sub;
    if (row >= NB_) return;
    int s = off[row], d = deg[row];
    float sum[8] = {0.f, 0.f, 0.f, 0.f, 0.f, 0.f, 0.f, 0.f};
    int k = 0;
    for (; k + 4 <= d; k += 4) {
        int c0 = cv[s + k + 0];
        int c1 = cv[s + k + 1];
        int c2 = cv[s + k + 2];
        int c3 = cv[s + k + 3];
        uint4 x0 = acc16[(size_t)(NU_ + c0) * 8 + l];
        uint4 x1 = acc16[(size_t)(NU_ + c1) * 8 + l];
        uint4 x2 = acc16[(size_t)(NU_ + c2) * 8 + l];
        uint4 x3 = acc16[(size_t)(NU_ + c3) * 8 + l];
        fma8(sum, 1.f, x0);
        fma8(sum, 1.f, x1);
        fma8(sum, 1.f, x2);
        fma8(sum, 1.f, x3);
    }
    for (; k < d; ++k) {
        int c = cv[s + k];
        uint4 x = acc16[(size_t)(NU_ + c) * 8 + l];
        fma8(sum, 1.f, x);
    }
    float scale = (1.0f / 3.0f) / ((float)d + 1e-8f);
    float4 o0, o1;
    o0.x = sum[0] * scale; o0.y = sum[1] * scale;
    o0.z = sum[2] * scale; o0.w = sum[3] * scale;
    o1.x = sum[4] * scale; o1.y = sum[5] * scale;
    o1.z = sum[6] * scale; o1.w = sum[7] * scale;
    float4* bp = (float4*)(brep + (size_t)row * DIM + l * 8);
    bp[0] = o0;
    bp[1] = o1;
}

// ---------------------------------------------------------------------------
__global__ void score_kernel(const unsigned short* __restrict__ acc16u,
                             const float* __restrict__ brep,
                             const int*   __restrict__ users,
                             const int*   __restrict__ bundles,
                             float* __restrict__ loss_sum) {
    int tid  = blockIdx.x * blockDim.x + threadIdx.x;
    int b    = tid >> 6;
    int lane = tid & 63;
    if (b >= BATCH) return;
    int u  = users[b];
    int b0 = bundles[2 * b];
    int b1 = bundles[2 * b + 1];
    float du = __uint_as_float((unsigned int)acc16u[(size_t)u * DIM + lane] << 16)
               * (1.0f / 3.0f);
    float d  = du * (brep[(size_t)b0 * DIM + lane] -
                     brep[(size_t)b1 * DIM + lane]);
    #pragma unroll
    for (int off = 32; off > 0; off >>= 1)
        d += __shfl_down(d, off, 64);
    if (lane == 0) {
        float x = d;
        float l = fmaxf(-x, 0.0f) + log1pf(expf(-fabsf(x)));
        atomicAdd(loss_sum, l);
    }
}

// ---------------------------------------------------------------------------
__global__ void finalize_kernel(const float* __restrict__ loss_sum,
                                float* __restrict__ out) {
    out[0] = loss_sum[0] * (1.0f / BATCH);
    out[1] = 0.0f;
}

// ---------------------------------------------------------------------------
extern "C" void kernel_launch(void* const* d_in, const int* in_sizes, int n_in,
                              void* d_out, int out_size, void* d_ws, size_t ws_size,
                              hipStream_t stream) {
    const float* uf        = (const float*)d_in[0];
    const float* itf       = (const float*)d_in[1];
    const int*   prop_rows = (const int*)  d_in[4];
    const int*   prop_cols = (const int*)  d_in[5];
    const int*   bi_rows   = (const int*)  d_in[6];
    const int*   bi_cols   = (const int*)  d_in[7];
    const int*   users     = (const int*)  d_in[8];
    const int*   bundles   = (const int*)  d_in[9];
    float* out = (float*)d_out;

    char* ws = (char*)d_ws;
    uint4*        acc16   = (uint4*)       (ws + 0);           // 19.2 MB
    uint4*        f1s16   = (uint4*)       (ws + 19200000);    // 19.2 MB
    uint4*        feats16 = (uint4*)       (ws + 38400000);    // 19.2 MB
    float*        brep    = (float*)       (ws + 57600000);    // 5.12 MB
    int*          cvP     = (int*)         (ws + 62720000);    // 16 MB
    unsigned int* binnedP = (unsigned int*)(ws + 78720000);    // 16 MB
    int*          cvB     = (int*)         (ws + 94720000);    // 2.4 MB
    unsigned int* binnedB = (unsigned int*)(ws + 97120000);    // 2.4 MB
    int*          degP    = (int*)         (ws + 99520000);
    int*          offP    = (int*)         (ws + 100120000);
    float*        invsP   = (float*)       (ws + 100720000);
    int*          degB    = (int*)         (ws + 101320000);
    int*          offB    = (int*)         (ws + 101400000);
    int*          bcntP   = (int*)         (ws + 101480000);
    int*          binoffP = (int*)         (ws + 101484096);
    int*          gcurP   = (int*)         (ws + 101488192);
    int*          bcntB   = (int*)         (ws + 101492288);
    int*          binoffB = (int*)         (ws + 101496384);
    int*          gcurB   = (int*)         (ws + 101500480);
    float*        loss    = (float*)       (ws + 101504576);

    hipMemsetAsync(bcntP, 0, (size_t)NBIN_P * 4, stream);
    hipMemsetAsync(bcntB, 0, (size_t)NBIN_B * 4, stream);
    hipMemsetAsync(loss,  0, 4, stream);

    // ---- bf16 cast of features ----
    cast_feats_kernel<<<(NTOT * 16 + 255) / 256, 256, 0, stream>>>(
        (const float4*)uf, (const float4*)itf, (uint2*)feats16);

    // ---- bin histograms ----
    hist_bins_kernel<NBIN_P><<<512, 256, 0, stream>>>(prop_rows, NPROP, bcntP);
    hist_bins_kernel<NBIN_B><<<256, 256, 0, stream>>>(bi_rows, E_BI_, bcntB);

    // ---- bin offsets / cursors ----
    scan_bins_kernel<NBIN_P><<<1, 1024, 0, stream>>>(bcntP, binoffP, gcurP);
    scan_bins_kernel<NBIN_B><<<1, 1024, 0, stream>>>(bcntB, binoffB, gcurB);

    // ---- pass 1: staged multisplit (4 edges/thread per barrier cycle) ----
    multisplit_kernel<NBIN_P><<<768, 256, 0, stream>>>(prop_rows, prop_cols,
                                                       NPROP, gcurP, binnedP);
    multisplit_kernel<NBIN_B><<<128, 256, 0, stream>>>(bi_rows, bi_cols,
                                                       E_BI_, gcurB, binnedB);

    // ---- pass 2: fused per-bin CSR ----
    bin_csr_kernel<<<NBIN_P, 256, 0, stream>>>(binnedP, binoffP, NPROP, NBIN_P,
                                               NTOT, offP, degP, invsP, cvP);
    bin_csr_kernel<<<NBIN_B, 256, 0, stream>>>(binnedB, binoffB, E_BI_, NBIN_B,
                                               NB_, offB, degB, (float*)0, cvB);

    // ---- propagation: 32 rows per 256-thread block ----
    layer1_kernel<<<(NTOT + 31) / 32, 256, 0, stream>>>(offP, degP, cvP, invsP,
                                                        feats16, f1s16, acc16);
    layer2_kernel<<<(NTOT + 31) / 32, 256, 0, stream>>>(offP, degP, cvP, invsP,
                                                        f1s16, acc16);
    bi_csr_kernel<<<(NB_ + 31) / 32, 256, 0, stream>>>(offB, degB, cvB, acc16, brep);

    // ---- loss ----
    score_kernel<<<BATCH * 64 / 256, 256, 0, stream>>>(
        (const unsigned short*)acc16, brep, users, bundles, loss);
    finalize_kernel<<<1, 1, 0, stream>>>(loss, out);
}